// Round 1
// baseline (1596.605 us; speedup 1.0000x reference)
//
#include <hip/hip_runtime.h>
#include <hip/hip_bf16.h>
#include <math.h>

// ---------------------------------------------------------------------------
// GraphMemoryNetwork: embed -> 3x {QKV, edge-softmax attention, O + LN} -> FFN
// Round 0: correctness-first fp32 implementation.
// N=50000, E=640000, D_IN=256, D=128, H=8, DH=16, NC=47, L=3
// ---------------------------------------------------------------------------

// ------------------------- CSR build ---------------------------------------

__global__ __launch_bounds__(256) void zero_ints(int* __restrict__ p, int n) {
    int i = blockIdx.x * 256 + threadIdx.x;
    if (i < n) p[i] = 0;
}

__global__ __launch_bounds__(256) void count_deg(const int* __restrict__ ei,
                                                 int* __restrict__ deg, int E) {
    int e = blockIdx.x * 256 + threadIdx.x;
    if (e < E) atomicAdd(&deg[ei[(size_t)E + e]], 1);   // dst = ei[1][e]
}

__global__ __launch_bounds__(1024) void scan_deg(const int* __restrict__ deg,
                                                 int* __restrict__ row_ptr, int N) {
    __shared__ int s[1024];
    __shared__ int carry_s;
    int t = threadIdx.x;
    if (t == 0) carry_s = 0;
    __syncthreads();
    for (int base = 0; base < N; base += 1024) {
        int x = (base + t < N) ? deg[base + t] : 0;
        s[t] = x;
        __syncthreads();
        for (int d = 1; d < 1024; d <<= 1) {
            int v = (t >= d) ? s[t - d] : 0;
            __syncthreads();
            s[t] += v;
            __syncthreads();
        }
        int incl = s[t];
        int c = carry_s;
        if (base + t < N) row_ptr[base + t] = c + incl - x;  // exclusive
        __syncthreads();
        if (t == 1023) carry_s = c + incl;
        __syncthreads();
    }
    if (t == 0) row_ptr[N] = carry_s;
}

__global__ __launch_bounds__(256) void scatter_edges(const int* __restrict__ ei,
                                                     const int* __restrict__ row_ptr,
                                                     int* __restrict__ cursor,
                                                     int* __restrict__ csr_src, int E) {
    int e = blockIdx.x * 256 + threadIdx.x;
    if (e < E) {
        int d = ei[(size_t)E + e];
        int pos = row_ptr[d] + atomicAdd(&cursor[d], 1);
        csr_src[pos] = ei[e];
    }
}

// ------------------------- generic fp32 GEMM --------------------------------
// C[M,Nmat] = act(A[M,K] @ B[K,Nmat] + bias). Tiles 64x64, BK=16, 4x4/thread.

template <int ACT>
__global__ __launch_bounds__(256) void gemm64(const float* __restrict__ A,
                                              const float* __restrict__ B,
                                              const float* __restrict__ bias,
                                              float* __restrict__ C,
                                              int M, int K, int Nmat) {
    __shared__ float As[16][64];
    __shared__ float Bs[16][64];
    int t = threadIdx.x;
    int m0 = blockIdx.x * 64;
    int n0 = blockIdx.y * 64;
    int tx = t & 15, ty = t >> 4;

    int am = t >> 2;            // 0..63
    int ak = (t & 3) << 2;      // 0,4,8,12
    int bk = t >> 4;            // 0..15
    int bn = (t & 15) << 2;     // 0..60

    float acc[4][4] = {};

    for (int k0 = 0; k0 < K; k0 += 16) {
        float4 av = make_float4(0.f, 0.f, 0.f, 0.f);
        int arow = m0 + am;
        if (arow < M) av = *(const float4*)&A[(size_t)arow * K + k0 + ak];
        As[ak + 0][am] = av.x;
        As[ak + 1][am] = av.y;
        As[ak + 2][am] = av.z;
        As[ak + 3][am] = av.w;
        float4 bv = *(const float4*)&B[(size_t)(k0 + bk) * Nmat + n0 + bn];
        *(float4*)&Bs[bk][bn] = bv;
        __syncthreads();
#pragma unroll
        for (int kk = 0; kk < 16; ++kk) {
            float a[4], b[4];
            *(float4*)a = *(const float4*)&As[kk][ty * 4];
            *(float4*)b = *(const float4*)&Bs[kk][tx * 4];
#pragma unroll
            for (int i = 0; i < 4; ++i)
#pragma unroll
                for (int j = 0; j < 4; ++j)
                    acc[i][j] = fmaf(a[i], b[j], acc[i][j]);
        }
        __syncthreads();
    }

#pragma unroll
    for (int i = 0; i < 4; ++i) {
        int row = m0 + ty * 4 + i;
        if (row >= M) continue;
#pragma unroll
        for (int j = 0; j < 4; ++j) {
            int col = n0 + tx * 4 + j;
            float v = acc[i][j];
            if (bias) v += bias[col];
            if (ACT) v = fmaxf(v, 0.f);
            C[(size_t)row * Nmat + col] = v;
        }
    }
}

// ------------------------- LayerNorm (D=128), optional residual -------------

__global__ __launch_bounds__(256) void ln128(const float* __restrict__ x,
                                             const float* __restrict__ res,
                                             const float* __restrict__ g,
                                             const float* __restrict__ b,
                                             float* __restrict__ out, int N) {
    int wave = threadIdx.x >> 6;
    int lane = threadIdx.x & 63;
    int n = blockIdx.x * 4 + wave;
    if (n >= N) return;
    float2 xv = *(const float2*)&x[(size_t)n * 128 + lane * 2];
    if (res) {
        float2 rv = *(const float2*)&res[(size_t)n * 128 + lane * 2];
        xv.x += rv.x;
        xv.y += rv.y;
    }
    float sum = xv.x + xv.y;
#pragma unroll
    for (int o = 1; o < 64; o <<= 1) sum += __shfl_xor(sum, o);
    float mu = sum * (1.f / 128.f);
    float d0 = xv.x - mu, d1 = xv.y - mu;
    float vs = d0 * d0 + d1 * d1;
#pragma unroll
    for (int o = 1; o < 64; o <<= 1) vs += __shfl_xor(vs, o);
    float rstd = rsqrtf(vs * (1.f / 128.f) + 1e-5f);
    float2 gv = *(const float2*)&g[lane * 2];
    float2 bv = *(const float2*)&b[lane * 2];
    float2 ov;
    ov.x = d0 * rstd * gv.x + bv.x;
    ov.y = d1 * rstd * gv.y + bv.y;
    *(float2*)&out[(size_t)n * 128 + lane * 2] = ov;
}

// ------------------------- attention (online softmax per node) --------------
// One wave per dst node. Lane l covers cols 2l, 2l+1 (head = l/8).
// Online softmax per head replicated across its 8 lanes.

__global__ __launch_bounds__(256) void attn_gat(const float* __restrict__ q,
                                                const float* __restrict__ k,
                                                const float* __restrict__ v,
                                                const int* __restrict__ row_ptr,
                                                const int* __restrict__ csr_src,
                                                float* __restrict__ agg, int N) {
    int wave = threadIdx.x >> 6;
    int lane = threadIdx.x & 63;
    int n = blockIdx.x * 4 + wave;
    if (n >= N) return;
    const float scale = 0.25f;  // 1/sqrt(DH=16)
    float2 qv = *(const float2*)&q[(size_t)n * 128 + lane * 2];
    float m = -INFINITY, s = 0.f, a0 = 0.f, a1 = 0.f;
    int e0 = row_ptr[n], e1 = row_ptr[n + 1];
    for (int e = e0; e < e1; ++e) {
        int src = csr_src[e];
        float2 kv = *(const float2*)&k[(size_t)src * 128 + lane * 2];
        float part = qv.x * kv.x + qv.y * kv.y;
        part += __shfl_xor(part, 1);
        part += __shfl_xor(part, 2);
        part += __shfl_xor(part, 4);
        float score = part * scale;
        float mn = fmaxf(m, score);
        float f = __expf(m - mn);       // m=-inf on first edge -> 0
        float p = __expf(score - mn);
        float2 vv = *(const float2*)&v[(size_t)src * 128 + lane * 2];
        s = s * f + p;
        a0 = a0 * f + p * vv.x;
        a1 = a1 * f + p * vv.y;
        m = mn;
    }
    float inv = (s > 0.f) ? 1.f / s : 0.f;   // deg-0 node -> agg = 0 (matches ref)
    float2 ov;
    ov.x = a0 * inv;
    ov.y = a1 * inv;
    *(float2*)&agg[(size_t)n * 128 + lane * 2] = ov;
}

// ------------------------- fused FFN head -----------------------------------
// Per block: 16 rows. h[16x128] -> h1[16x512] -> h2[16x512] -> out[16x47].
// LDS = 8KB + 32KB + 32KB = 72KB (2 blocks/CU).

__global__ __launch_bounds__(256) void ffn_head(const float* __restrict__ h,
                                                const float* __restrict__ f1w,
                                                const float* __restrict__ f1b,
                                                const float* __restrict__ f2w,
                                                const float* __restrict__ f2b,
                                                const float* __restrict__ f3w,
                                                const float* __restrict__ f3b,
                                                float* __restrict__ out, int N) {
    __shared__ float hs[16][128];
    __shared__ float h1s[16][512];
    __shared__ float h2s[16][512];
    int t = threadIdx.x;
    int r0 = blockIdx.x * 16;

#pragma unroll
    for (int it = 0; it < 2; ++it) {
        int idx = t + it * 256;
        int r = idx >> 5;
        int c = (idx & 31) << 2;
        int row = r0 + r;
        float4 v = (row < N) ? *(const float4*)&h[(size_t)row * 128 + c]
                             : make_float4(0.f, 0.f, 0.f, 0.f);
        *(float4*)&hs[r][c] = v;
    }
    __syncthreads();

    int cg = (t & 127) << 2;   // col group: 4 cols
    int rg = (t >> 7) << 3;    // row group: 8 rows
    float acc[8][4];

    // phase 1: h1 = relu(hs @ f1w + f1b), K=128
#pragma unroll
    for (int r = 0; r < 8; ++r)
        acc[r][0] = acc[r][1] = acc[r][2] = acc[r][3] = 0.f;
    for (int k4 = 0; k4 < 32; ++k4) {
        float4 xr[8];
#pragma unroll
        for (int r = 0; r < 8; ++r) xr[r] = *(const float4*)&hs[rg + r][k4 * 4];
#pragma unroll
        for (int kk = 0; kk < 4; ++kk) {
            float4 w = *(const float4*)&f1w[(size_t)(k4 * 4 + kk) * 512 + cg];
#pragma unroll
            for (int r = 0; r < 8; ++r) {
                float x = kk == 0 ? xr[r].x : kk == 1 ? xr[r].y : kk == 2 ? xr[r].z : xr[r].w;
                acc[r][0] = fmaf(x, w.x, acc[r][0]);
                acc[r][1] = fmaf(x, w.y, acc[r][1]);
                acc[r][2] = fmaf(x, w.z, acc[r][2]);
                acc[r][3] = fmaf(x, w.w, acc[r][3]);
            }
        }
    }
    {
        float4 bb = *(const float4*)&f1b[cg];
#pragma unroll
        for (int r = 0; r < 8; ++r) {
            h1s[rg + r][cg + 0] = fmaxf(acc[r][0] + bb.x, 0.f);
            h1s[rg + r][cg + 1] = fmaxf(acc[r][1] + bb.y, 0.f);
            h1s[rg + r][cg + 2] = fmaxf(acc[r][2] + bb.z, 0.f);
            h1s[rg + r][cg + 3] = fmaxf(acc[r][3] + bb.w, 0.f);
        }
    }
    __syncthreads();

    // phase 2: h2 = relu(h1s @ f2w + f2b), K=512
#pragma unroll
    for (int r = 0; r < 8; ++r)
        acc[r][0] = acc[r][1] = acc[r][2] = acc[r][3] = 0.f;
    for (int k4 = 0; k4 < 128; ++k4) {
        float4 xr[8];
#pragma unroll
        for (int r = 0; r < 8; ++r) xr[r] = *(const float4*)&h1s[rg + r][k4 * 4];
#pragma unroll
        for (int kk = 0; kk < 4; ++kk) {
            float4 w = *(const float4*)&f2w[(size_t)(k4 * 4 + kk) * 512 + cg];
#pragma unroll
            for (int r = 0; r < 8; ++r) {
                float x = kk == 0 ? xr[r].x : kk == 1 ? xr[r].y : kk == 2 ? xr[r].z : xr[r].w;
                acc[r][0] = fmaf(x, w.x, acc[r][0]);
                acc[r][1] = fmaf(x, w.y, acc[r][1]);
                acc[r][2] = fmaf(x, w.z, acc[r][2]);
                acc[r][3] = fmaf(x, w.w, acc[r][3]);
            }
        }
    }
    {
        float4 bb = *(const float4*)&f2b[cg];
#pragma unroll
        for (int r = 0; r < 8; ++r) {
            h2s[rg + r][cg + 0] = fmaxf(acc[r][0] + bb.x, 0.f);
            h2s[rg + r][cg + 1] = fmaxf(acc[r][1] + bb.y, 0.f);
            h2s[rg + r][cg + 2] = fmaxf(acc[r][2] + bb.z, 0.f);
            h2s[rg + r][cg + 3] = fmaxf(acc[r][3] + bb.w, 0.f);
        }
    }
    __syncthreads();

    // phase 3: out = h2s @ f3w + f3b, [16,47], K=512
    {
        int r = t >> 4;
        int c0 = t & 15;
        bool has2 = (c0 + 32) < 47;
        int c2 = has2 ? c0 + 32 : 0;
        float a0 = f3b[c0], a1 = f3b[c0 + 16], a2 = has2 ? f3b[c2] : 0.f;
        for (int k4 = 0; k4 < 128; ++k4) {
            float4 xr = *(const float4*)&h2s[r][k4 * 4];
#pragma unroll
            for (int kk = 0; kk < 4; ++kk) {
                float x = kk == 0 ? xr.x : kk == 1 ? xr.y : kk == 2 ? xr.z : xr.w;
                const float* wr = &f3w[(size_t)(k4 * 4 + kk) * 47];
                a0 = fmaf(x, wr[c0], a0);
                a1 = fmaf(x, wr[c0 + 16], a1);
                a2 = fmaf(x, wr[c2], a2);
            }
        }
        int row = r0 + r;
        if (row < N) {
            out[(size_t)row * 47 + c0] = a0;
            out[(size_t)row * 47 + c0 + 16] = a1;
            if (has2) out[(size_t)row * 47 + c0 + 32] = a2;
        }
    }
}

// ------------------------- launch -------------------------------------------

extern "C" void kernel_launch(void* const* d_in, const int* in_sizes, int n_in,
                              void* d_out, int out_size, void* d_ws, size_t ws_size,
                              hipStream_t stream) {
    const float* X        = (const float*)d_in[0];
    const int*   ei       = (const int*)d_in[1];
    const float* emb_w    = (const float*)d_in[2];
    const float* emb_b    = (const float*)d_in[3];
    const float* emb_ln_g = (const float*)d_in[4];
    const float* emb_ln_b = (const float*)d_in[5];
    const float* Wq       = (const float*)d_in[6];
    const float* Wk       = (const float*)d_in[7];
    const float* Wv       = (const float*)d_in[8];
    const float* Wo       = (const float*)d_in[9];
    const float* ln_g     = (const float*)d_in[10];
    const float* ln_b     = (const float*)d_in[11];
    const float* f1w      = (const float*)d_in[12];
    const float* f1b      = (const float*)d_in[13];
    const float* f2w      = (const float*)d_in[14];
    const float* f2b      = (const float*)d_in[15];
    const float* f3w      = (const float*)d_in[16];
    const float* f3b      = (const float*)d_in[17];

    const int N = in_sizes[0] / 256;  // 50000
    const int E = in_sizes[1] / 2;    // 640000
    const int L = 3;

    // ws layout (floats then ints): ~131 MB
    float* h   = (float*)d_ws;
    float* q   = h + (size_t)N * 128;
    float* kb  = q + (size_t)N * 128;
    float* vb  = kb + (size_t)N * 128;
    float* agg = vb + (size_t)N * 128;
    int* deg     = (int*)(agg + (size_t)N * 128);
    int* cursor  = deg + N;
    int* row_ptr = cursor + N;
    int* csr_src = row_ptr + (N + 1);

    // CSR build (per call; deterministic work)
    zero_ints<<<(2 * N + 255) / 256, 256, 0, stream>>>(deg, 2 * N);
    count_deg<<<(E + 255) / 256, 256, 0, stream>>>(ei, deg, E);
    scan_deg<<<1, 1024, 0, stream>>>(deg, row_ptr, N);
    scatter_edges<<<(E + 255) / 256, 256, 0, stream>>>(ei, row_ptr, cursor, csr_src, E);

    dim3 g128((N + 63) / 64, 2);

    // embedding: relu(X @ emb_w + emb_b) -> LN -> h
    gemm64<1><<<g128, 256, 0, stream>>>(X, emb_w, emb_b, q, N, 256, 128);
    ln128<<<(N + 3) / 4, 256, 0, stream>>>(q, nullptr, emb_ln_g, emb_ln_b, h, N);

    for (int l = 0; l < L; ++l) {
        const float* wq = Wq + (size_t)l * 128 * 128;
        const float* wk = Wk + (size_t)l * 128 * 128;
        const float* wv = Wv + (size_t)l * 128 * 128;
        const float* wo = Wo + (size_t)l * 128 * 128;
        gemm64<0><<<g128, 256, 0, stream>>>(h, wq, nullptr, q, N, 128, 128);
        gemm64<0><<<g128, 256, 0, stream>>>(h, wk, nullptr, kb, N, 128, 128);
        gemm64<0><<<g128, 256, 0, stream>>>(h, wv, nullptr, vb, N, 128, 128);
        attn_gat<<<(N + 3) / 4, 256, 0, stream>>>(q, kb, vb, row_ptr, csr_src, agg, N);
        // tmp_o reuses q (q dead after attention)
        gemm64<0><<<g128, 256, 0, stream>>>(agg, wo, nullptr, q, N, 128, 128);
        ln128<<<(N + 3) / 4, 256, 0, stream>>>(h, q, ln_g + (size_t)l * 128,
                                               ln_b + (size_t)l * 128, h, N);
    }

    ffn_head<<<(N + 15) / 16, 256, 0, stream>>>(h, f1w, f1b, f2w, f2b, f3w, f3b,
                                                (float*)d_out, N);
}

// Round 2
// 728.006 us; speedup vs baseline: 2.1931x; 2.1931x over previous
//
#include <hip/hip_runtime.h>
#include <hip/hip_bf16.h>
#include <math.h>

// ---------------------------------------------------------------------------
// GraphMemoryNetwork — Round 1: bf16 MFMA everywhere.
// N=50000, E=640000, D_IN=256, D=128, H=8, DH=16, NC=47, L=3
// ---------------------------------------------------------------------------

typedef __bf16 bf16x8 __attribute__((ext_vector_type(8)));
typedef __bf16 bf16x4 __attribute__((ext_vector_type(4)));
typedef __bf16 bf16x2 __attribute__((ext_vector_type(2)));
typedef float  f32x4  __attribute__((ext_vector_type(4)));

#define MFMA16(a, b, c) __builtin_amdgcn_mfma_f32_16x16x32_bf16((a), (b), (c), 0, 0, 0)

// ------------------------- CSR build ---------------------------------------

__global__ __launch_bounds__(256) void zero_ints(int* __restrict__ p, int n) {
    int i = blockIdx.x * 256 + threadIdx.x;
    if (i < n) p[i] = 0;
}

__global__ __launch_bounds__(256) void count_deg(const int* __restrict__ ei,
                                                 int* __restrict__ deg, int E) {
    int e = blockIdx.x * 256 + threadIdx.x;
    if (e < E) atomicAdd(&deg[ei[(size_t)E + e]], 1);   // dst = ei[1][e]
}

__global__ __launch_bounds__(1024) void scan_deg(const int* __restrict__ deg,
                                                 int* __restrict__ row_ptr, int N) {
    __shared__ int wsum[16];
    __shared__ int carry_s;
    int t = threadIdx.x, lane = t & 63, w = t >> 6;
    if (t == 0) carry_s = 0;
    __syncthreads();
    for (int base = 0; base < N; base += 1024) {
        int x = (base + t < N) ? deg[base + t] : 0;
        int incl = x;
#pragma unroll
        for (int o = 1; o < 64; o <<= 1) {
            int v = __shfl_up(incl, o);
            if (lane >= o) incl += v;
        }
        if (lane == 63) wsum[w] = incl;
        __syncthreads();
        if (w == 0 && lane < 16) {
            int v = wsum[lane];
            int s = v;
#pragma unroll
            for (int o = 1; o < 16; o <<= 1) {
                int u = __shfl_up(s, o);
                if (lane >= o) s += u;
            }
            wsum[lane] = s - v;  // exclusive prefix of wave sums
        }
        __syncthreads();
        int c = carry_s;
        if (base + t < N) row_ptr[base + t] = c + wsum[w] + incl - x;
        __syncthreads();
        if (t == 1023) carry_s = c + wsum[15] + incl;
        __syncthreads();
    }
    if (t == 0) row_ptr[N] = carry_s;
}

__global__ __launch_bounds__(256) void scatter_edges(const int* __restrict__ ei,
                                                     const int* __restrict__ row_ptr,
                                                     int* __restrict__ cursor,
                                                     int* __restrict__ csr_src, int E) {
    int e = blockIdx.x * 256 + threadIdx.x;
    if (e < E) {
        int d = ei[(size_t)E + e];
        int pos = row_ptr[d] + atomicAdd(&cursor[d], 1);
        csr_src[pos] = ei[e];
    }
}

// ------------------------- converts ----------------------------------------

// out[n][k] = (bf16) in[k][n]; in is [K][Nin] fp32, out is [Npad][K] bf16
// (rows n in [Nin, Npad) zero-filled).
__global__ __launch_bounds__(256) void transpose_bf16(const float* __restrict__ in,
                                                      __bf16* __restrict__ out,
                                                      int K, int Nin, int Npad) {
    __shared__ float tile[32][33];
    int n0 = blockIdx.x * 32, k0 = blockIdx.y * 32;
    int tx = threadIdx.x & 31, ty = threadIdx.x >> 5;
#pragma unroll
    for (int i = 0; i < 32; i += 8) {
        int k = k0 + ty + i, n = n0 + tx;
        tile[ty + i][tx] = (k < K && n < Nin) ? in[(size_t)k * Nin + n] : 0.f;
    }
    __syncthreads();
#pragma unroll
    for (int i = 0; i < 32; i += 8) {
        int n = n0 + ty + i, k = k0 + tx;
        if (n < Npad && k < K) out[(size_t)n * K + k] = (__bf16)tile[tx][ty + i];
    }
}

__global__ __launch_bounds__(256) void cvt_bf16_vec(const float* __restrict__ in,
                                                    __bf16* __restrict__ out, int n4) {
    int i = blockIdx.x * 256 + threadIdx.x;
    if (i < n4) {
        float4 v = ((const float4*)in)[i];
        bf16x4 o;
        o[0] = (__bf16)v.x; o[1] = (__bf16)v.y; o[2] = (__bf16)v.z; o[3] = (__bf16)v.w;
        ((bf16x4*)out)[i] = o;
    }
}

// ------------------------- plain MFMA GEMM (C bf16) -------------------------
// One wave per 16 output rows, full Nmat width. A [M][K] bf16, BT [Nmat][K] bf16.
// No LDS, no barriers: B fragments stream from L2.

template <int K, int NTILES>
__global__ __launch_bounds__(256) void gemm_bf16(const __bf16* __restrict__ A,
                                                 const __bf16* __restrict__ BT,
                                                 __bf16* __restrict__ C, int M) {
    int wid = (blockIdx.x * 256 + threadIdx.x) >> 6;
    int lane = threadIdx.x & 63;
    int m0 = wid * 16;
    if (m0 >= M) return;
    constexpr int KS = K / 32;
    constexpr int NMAT = NTILES * 16;
    int cb = lane & 15;
    int kc = (lane >> 4) * 8;
    int rq = (lane >> 4) * 4;

    bf16x8 a[KS];
#pragma unroll
    for (int ks = 0; ks < KS; ++ks)
        a[ks] = *(const bf16x8*)&A[(size_t)(m0 + cb) * K + ks * 32 + kc];

#pragma unroll
    for (int nt = 0; nt < NTILES; ++nt) {
        f32x4 acc = {0.f, 0.f, 0.f, 0.f};
        const __bf16* bp = &BT[(size_t)(nt * 16 + cb) * K + kc];
#pragma unroll
        for (int ks = 0; ks < KS; ++ks) {
            bf16x8 b = *(const bf16x8*)&bp[ks * 32];
            acc = MFMA16(a[ks], b, acc);
        }
        int col = nt * 16 + cb;
#pragma unroll
        for (int i = 0; i < 4; ++i)
            C[(size_t)(m0 + rq + i) * NMAT + col] = (__bf16)acc[i];
    }
}

// ------------------------- MFMA GEMM + fused LayerNorm ----------------------
// Nmat = 128 (full row per wave). EMB: y = LN(relu(A@B + bias)); else:
// y = LN(resid + A@B). Writes fp32 hout and bf16 hbf.

template <int K, bool EMB>
__global__ __launch_bounds__(256) void gemm_ln(const __bf16* __restrict__ A,
                                               const __bf16* __restrict__ BT,
                                               const float* __restrict__ bias,
                                               const float* resid,
                                               const float* __restrict__ g,
                                               const float* __restrict__ beta,
                                               float* hout, __bf16* __restrict__ hbf,
                                               int M) {
    int wid = (blockIdx.x * 256 + threadIdx.x) >> 6;
    int lane = threadIdx.x & 63;
    int m0 = wid * 16;
    if (m0 >= M) return;
    constexpr int KS = K / 32;
    int cb = lane & 15;
    int kc = (lane >> 4) * 8;
    int rq = (lane >> 4) * 4;

    bf16x8 a[KS];
#pragma unroll
    for (int ks = 0; ks < KS; ++ks)
        a[ks] = *(const bf16x8*)&A[(size_t)(m0 + cb) * K + ks * 32 + kc];

    f32x4 acc[8];
#pragma unroll
    for (int nt = 0; nt < 8; ++nt) acc[nt] = (f32x4){0.f, 0.f, 0.f, 0.f};
#pragma unroll
    for (int nt = 0; nt < 8; ++nt) {
        const __bf16* bp = &BT[(size_t)(nt * 16 + cb) * K + kc];
#pragma unroll
        for (int ks = 0; ks < KS; ++ks) {
            bf16x8 b = *(const bf16x8*)&bp[ks * 32];
            acc[nt] = MFMA16(a[ks], b, acc[nt]);
        }
    }

    // epilogue: bias/relu or residual
#pragma unroll
    for (int nt = 0; nt < 8; ++nt) {
        int col = nt * 16 + cb;
        float bb = EMB ? bias[col] : 0.f;
#pragma unroll
        for (int i = 0; i < 4; ++i) {
            float v = acc[nt][i];
            if (EMB) {
                v = fmaxf(v + bb, 0.f);
            } else {
                v += resid[(size_t)(m0 + rq + i) * 128 + col];
            }
            acc[nt][i] = v;
        }
    }

    // per-row LN stats: rows live in 16-lane groups (l>>4 fixed)
    float s[4] = {0.f, 0.f, 0.f, 0.f}, qs[4] = {0.f, 0.f, 0.f, 0.f};
#pragma unroll
    for (int nt = 0; nt < 8; ++nt)
#pragma unroll
        for (int i = 0; i < 4; ++i) {
            float v = acc[nt][i];
            s[i] += v;
            qs[i] += v * v;
        }
#pragma unroll
    for (int i = 0; i < 4; ++i)
#pragma unroll
        for (int o = 1; o < 16; o <<= 1) {
            s[i] += __shfl_xor(s[i], o);
            qs[i] += __shfl_xor(qs[i], o);
        }
    float mu[4], rstd[4];
#pragma unroll
    for (int i = 0; i < 4; ++i) {
        mu[i] = s[i] * (1.f / 128.f);
        float var = qs[i] * (1.f / 128.f) - mu[i] * mu[i];
        rstd[i] = rsqrtf(var + 1e-5f);
    }

#pragma unroll
    for (int nt = 0; nt < 8; ++nt) {
        int col = nt * 16 + cb;
        float gv = g[col], bv = beta[col];
#pragma unroll
        for (int i = 0; i < 4; ++i) {
            float y = (acc[nt][i] - mu[i]) * rstd[i] * gv + bv;
            size_t idx = (size_t)(m0 + rq + i) * 128 + col;
            hout[idx] = y;
            hbf[idx] = (__bf16)y;
        }
    }
}

// ------------------------- attention (bf16, dual-stream online softmax) -----
// qkv [N][384] bf16 (q:0-127, k:128-255, v:256-383). One wave per dst node,
// lane covers 2 channels; per-head 8-lane shfl reduce.

__global__ __launch_bounds__(256) void attn_gat(const __bf16* __restrict__ qkv,
                                                const int* __restrict__ row_ptr,
                                                const int* __restrict__ csr_src,
                                                __bf16* __restrict__ agg, int N) {
    int wave = threadIdx.x >> 6;
    int lane = threadIdx.x & 63;
    int n = blockIdx.x * 4 + wave;
    if (n >= N) return;
    const float scale = 0.25f;  // 1/sqrt(16)
    bf16x2 q2 = *(const bf16x2*)&qkv[(size_t)n * 384 + lane * 2];
    float qx = (float)q2[0], qy = (float)q2[1];
    int e0 = row_ptr[n], e1 = row_ptr[n + 1];

    float mA = -3e38f, sA = 0.f, aA0 = 0.f, aA1 = 0.f;
    float mB = -3e38f, sB = 0.f, aB0 = 0.f, aB1 = 0.f;

    int e = e0;
    for (; e + 1 < e1; e += 2) {
        int s0 = csr_src[e], s1 = csr_src[e + 1];
        const __bf16* p0 = &qkv[(size_t)s0 * 384 + 128 + lane * 2];
        const __bf16* p1 = &qkv[(size_t)s1 * 384 + 128 + lane * 2];
        bf16x2 k0 = *(const bf16x2*)p0;
        bf16x2 k1 = *(const bf16x2*)p1;
        bf16x2 v0 = *(const bf16x2*)(p0 + 128);
        bf16x2 v1 = *(const bf16x2*)(p1 + 128);
        float d0 = qx * (float)k0[0] + qy * (float)k0[1];
        float d1 = qx * (float)k1[0] + qy * (float)k1[1];
        d0 += __shfl_xor(d0, 1); d1 += __shfl_xor(d1, 1);
        d0 += __shfl_xor(d0, 2); d1 += __shfl_xor(d1, 2);
        d0 += __shfl_xor(d0, 4); d1 += __shfl_xor(d1, 4);
        float sc0 = d0 * scale, sc1 = d1 * scale;
        {
            float mn = fmaxf(mA, sc0);
            float f = __expf(mA - mn), p = __expf(sc0 - mn);
            sA = sA * f + p;
            aA0 = aA0 * f + p * (float)v0[0];
            aA1 = aA1 * f + p * (float)v0[1];
            mA = mn;
        }
        {
            float mn = fmaxf(mB, sc1);
            float f = __expf(mB - mn), p = __expf(sc1 - mn);
            sB = sB * f + p;
            aB0 = aB0 * f + p * (float)v1[0];
            aB1 = aB1 * f + p * (float)v1[1];
            mB = mn;
        }
    }
    if (e < e1) {  // tail edge
        int s0 = csr_src[e];
        const __bf16* p0 = &qkv[(size_t)s0 * 384 + 128 + lane * 2];
        bf16x2 k0 = *(const bf16x2*)p0;
        bf16x2 v0 = *(const bf16x2*)(p0 + 128);
        float d0 = qx * (float)k0[0] + qy * (float)k0[1];
        d0 += __shfl_xor(d0, 1);
        d0 += __shfl_xor(d0, 2);
        d0 += __shfl_xor(d0, 4);
        float sc0 = d0 * scale;
        float mn = fmaxf(mA, sc0);
        float f = __expf(mA - mn), p = __expf(sc0 - mn);
        sA = sA * f + p;
        aA0 = aA0 * f + p * (float)v0[0];
        aA1 = aA1 * f + p * (float)v0[1];
        mA = mn;
    }
    // merge streams
    float m = fmaxf(mA, mB);
    float fA = __expf(mA - m), fB = __expf(mB - m);
    float ssum = sA * fA + sB * fB;
    float a0 = aA0 * fA + aB0 * fB;
    float a1 = aA1 * fA + aB1 * fB;
    float inv = (ssum > 0.f) ? 1.f / ssum : 0.f;
    bf16x2 o;
    o[0] = (__bf16)(a0 * inv);
    o[1] = (__bf16)(a1 * inv);
    *(bf16x2*)&agg[(size_t)n * 128 + lane * 2] = o;
}

// ------------------------- FFN head (MFMA, 3 phases) ------------------------
// Block = 256 threads (4 waves), 64 rows. h[64][128] -> h1[64][512] (LDS,
// XOR-swizzled) -> h2 (aliased onto same LDS) -> out[64][47].

__global__ __launch_bounds__(256) void ffn_mfma(const __bf16* __restrict__ hbf,
                                                const __bf16* __restrict__ f1T,
                                                const float* __restrict__ f1b,
                                                const __bf16* __restrict__ f2T,
                                                const float* __restrict__ f2b,
                                                const __bf16* __restrict__ f3T,
                                                const float* __restrict__ f3b,
                                                float* __restrict__ out, int M) {
    __shared__ __bf16 hbuf[64 * 512];  // 64 KB; byte addr = rl*1024+col*2, ^(rl&7)<<4
    int w = threadIdx.x >> 6;
    int lane = threadIdx.x & 63;
    int r0 = blockIdx.x * 64;
    int cb = lane & 15;
    int kc = (lane >> 4) * 8;
    int rq = (lane >> 4) * 4;
    char* hb = (char*)hbuf;

    // ---- phase 1: h1 = relu(h @ f1w + b1); wave w owns cols [w*128, w*128+128)
    bf16x8 a1[4][4];
#pragma unroll
    for (int mt = 0; mt < 4; ++mt) {
        int row = r0 + mt * 16 + cb;
        if (row >= M) row = M - 1;
#pragma unroll
        for (int ks = 0; ks < 4; ++ks)
            a1[mt][ks] = *(const bf16x8*)&hbf[(size_t)row * 128 + ks * 32 + kc];
    }
#pragma unroll
    for (int nt = 0; nt < 8; ++nt) {
        int ncol = w * 128 + nt * 16;
        f32x4 acc[4];
#pragma unroll
        for (int mt = 0; mt < 4; ++mt) acc[mt] = (f32x4){0.f, 0.f, 0.f, 0.f};
#pragma unroll
        for (int ks = 0; ks < 4; ++ks) {
            bf16x8 b = *(const bf16x8*)&f1T[(size_t)(ncol + cb) * 128 + ks * 32 + kc];
#pragma unroll
            for (int mt = 0; mt < 4; ++mt) acc[mt] = MFMA16(a1[mt][ks], b, acc[mt]);
        }
        float bb = f1b[ncol + cb];
#pragma unroll
        for (int mt = 0; mt < 4; ++mt)
#pragma unroll
            for (int i = 0; i < 4; ++i) {
                int rl = mt * 16 + rq + i;
                int byte = (rl * 1024 + (ncol + cb) * 2) ^ ((rl & 7) << 4);
                *(__bf16*)(hb + byte) = (__bf16)fmaxf(acc[mt][i] + bb, 0.f);
            }
    }
    __syncthreads();

    // ---- phase 2: h2 = relu(h1 @ f2w + b2); K=512, same col ownership
    f32x4 acc2[4][8];
#pragma unroll
    for (int mt = 0; mt < 4; ++mt)
#pragma unroll
        for (int nt = 0; nt < 8; ++nt) acc2[mt][nt] = (f32x4){0.f, 0.f, 0.f, 0.f};
    for (int ks = 0; ks < 16; ++ks) {
        bf16x8 a2[4];
#pragma unroll
        for (int mt = 0; mt < 4; ++mt) {
            int rl = mt * 16 + cb;
            int byte = (rl * 1024 + (ks * 32 + kc) * 2) ^ ((rl & 7) << 4);
            a2[mt] = *(const bf16x8*)(hb + byte);
        }
#pragma unroll
        for (int nt = 0; nt < 8; ++nt) {
            int ncol = w * 128 + nt * 16;
            bf16x8 b = *(const bf16x8*)&f2T[(size_t)(ncol + cb) * 512 + ks * 32 + kc];
#pragma unroll
            for (int mt = 0; mt < 4; ++mt) acc2[mt][nt] = MFMA16(a2[mt], b, acc2[mt][nt]);
        }
    }
    __syncthreads();  // all h1 reads complete before overwrite
#pragma unroll
    for (int nt = 0; nt < 8; ++nt) {
        int ncol = w * 128 + nt * 16;
        float bb = f2b[ncol + cb];
#pragma unroll
        for (int mt = 0; mt < 4; ++mt)
#pragma unroll
            for (int i = 0; i < 4; ++i) {
                int rl = mt * 16 + rq + i;
                int byte = (rl * 1024 + (ncol + cb) * 2) ^ ((rl & 7) << 4);
                *(__bf16*)(hb + byte) = (__bf16)fmaxf(acc2[mt][nt][i] + bb, 0.f);
            }
    }
    __syncthreads();

    // ---- phase 3: out = h2 @ f3w + b3; wave w owns m-tile w (16 rows), 3 n-tiles
    f32x4 acc3[3];
#pragma unroll
    for (int nt = 0; nt < 3; ++nt) acc3[nt] = (f32x4){0.f, 0.f, 0.f, 0.f};
    for (int ks = 0; ks < 16; ++ks) {
        int rl = w * 16 + cb;
        int byte = (rl * 1024 + (ks * 32 + kc) * 2) ^ ((rl & 7) << 4);
        bf16x8 a3 = *(const bf16x8*)(hb + byte);
#pragma unroll
        for (int nt = 0; nt < 3; ++nt) {
            bf16x8 b = *(const bf16x8*)&f3T[(size_t)(nt * 16 + cb) * 512 + ks * 32 + kc];
            acc3[nt] = MFMA16(a3, b, acc3[nt]);
        }
    }
#pragma unroll
    for (int nt = 0; nt < 3; ++nt) {
        int col = nt * 16 + cb;
        if (col < 47) {
            float bb = f3b[col];
            int r = r0 + w * 16 + rq;
#pragma unroll
            for (int i = 0; i < 4; ++i)
                if (r + i < M) out[(size_t)(r + i) * 47 + col] = acc3[nt][i] + bb;
        }
    }
}

// ------------------------- launch -------------------------------------------

extern "C" void kernel_launch(void* const* d_in, const int* in_sizes, int n_in,
                              void* d_out, int out_size, void* d_ws, size_t ws_size,
                              hipStream_t stream) {
    const float* X        = (const float*)d_in[0];
    const int*   ei       = (const int*)d_in[1];
    const float* emb_w    = (const float*)d_in[2];
    const float* emb_b    = (const float*)d_in[3];
    const float* emb_ln_g = (const float*)d_in[4];
    const float* emb_ln_b = (const float*)d_in[5];
    const float* Wq       = (const float*)d_in[6];
    const float* Wk       = (const float*)d_in[7];
    const float* Wv       = (const float*)d_in[8];
    const float* Wo       = (const float*)d_in[9];
    const float* ln_g     = (const float*)d_in[10];
    const float* ln_b     = (const float*)d_in[11];
    const float* f1w      = (const float*)d_in[12];
    const float* f1b      = (const float*)d_in[13];
    const float* f2w      = (const float*)d_in[14];
    const float* f2b      = (const float*)d_in[15];
    const float* f3w      = (const float*)d_in[16];
    const float* f3b      = (const float*)d_in[17];

    const int N = in_sizes[0] / 256;  // 50000
    const int E = in_sizes[1] / 2;    // 640000

    // ---- workspace layout
    char* p = (char*)d_ws;
    float* h = (float*)p;            p += (size_t)N * 128 * 4;
    __bf16* hbf = (__bf16*)p;        p += (size_t)N * 128 * 2;
    __bf16* qkv = (__bf16*)p;        p += (size_t)N * 384 * 2;
    __bf16* aggb = (__bf16*)p;       p += (size_t)N * 128 * 2;
    __bf16* Xbf = (__bf16*)p;        p += (size_t)N * 256 * 2;
    __bf16* embT = (__bf16*)p;       p += 128 * 256 * 2;
    __bf16* qkvT = (__bf16*)p;       p += 3 * 384 * 128 * 2;
    __bf16* woT = (__bf16*)p;        p += 3 * 128 * 128 * 2;
    __bf16* f1T = (__bf16*)p;        p += 512 * 128 * 2;
    __bf16* f2T = (__bf16*)p;        p += 512 * 512 * 2;
    __bf16* f3T = (__bf16*)p;        p += 48 * 512 * 2;
    int* deg = (int*)p;              p += (size_t)N * 4;
    int* cursor = (int*)p;           p += (size_t)N * 4;
    int* row_ptr = (int*)p;          p += (size_t)(N + 1) * 4;
    int* csr_src = (int*)p;

    // ---- CSR build
    zero_ints<<<(2 * N + 255) / 256, 256, 0, stream>>>(deg, 2 * N);
    count_deg<<<(E + 255) / 256, 256, 0, stream>>>(ei, deg, E);
    scan_deg<<<1, 1024, 0, stream>>>(deg, row_ptr, N);
    scatter_edges<<<(E + 255) / 256, 256, 0, stream>>>(ei, row_ptr, cursor, csr_src, E);

    // ---- weight converts (transposed bf16)
    cvt_bf16_vec<<<(N * 256 / 4 + 255) / 256, 256, 0, stream>>>(X, Xbf, N * 256 / 4);
    transpose_bf16<<<dim3(4, 8), 256, 0, stream>>>(emb_w, embT, 256, 128, 128);
    for (int l = 0; l < 3; ++l) {
        transpose_bf16<<<dim3(4, 4), 256, 0, stream>>>(Wq + (size_t)l * 16384,
                                                       qkvT + (size_t)l * 384 * 128, 128, 128, 128);
        transpose_bf16<<<dim3(4, 4), 256, 0, stream>>>(Wk + (size_t)l * 16384,
                                                       qkvT + (size_t)l * 384 * 128 + 128 * 128, 128, 128, 128);
        transpose_bf16<<<dim3(4, 4), 256, 0, stream>>>(Wv + (size_t)l * 16384,
                                                       qkvT + (size_t)l * 384 * 128 + 256 * 128, 128, 128, 128);
        transpose_bf16<<<dim3(4, 4), 256, 0, stream>>>(Wo + (size_t)l * 16384,
                                                       woT + (size_t)l * 128 * 128, 128, 128, 128);
    }
    transpose_bf16<<<dim3(16, 4), 256, 0, stream>>>(f1w, f1T, 128, 512, 512);
    transpose_bf16<<<dim3(16, 16), 256, 0, stream>>>(f2w, f2T, 512, 512, 512);
    transpose_bf16<<<dim3(2, 16), 256, 0, stream>>>(f3w, f3T, 512, 47, 48);

    int gw = ((N + 15) / 16 + 3) / 4;  // blocks of 4 waves, wave per 16 rows

    // ---- embedding: LN(relu(X @ emb_w + emb_b)) -> h (fp32) + hbf
    gemm_ln<256, true><<<gw, 256, 0, stream>>>(Xbf, embT, emb_b, nullptr,
                                               emb_ln_g, emb_ln_b, h, hbf, N);

    // ---- layers
    for (int l = 0; l < 3; ++l) {
        gemm_bf16<128, 24><<<gw, 256, 0, stream>>>(hbf, qkvT + (size_t)l * 384 * 128,
                                                   qkv, N);
        attn_gat<<<(N + 3) / 4, 256, 0, stream>>>(qkv, row_ptr, csr_src, aggb, N);
        gemm_ln<128, false><<<gw, 256, 0, stream>>>(aggb, woT + (size_t)l * 128 * 128,
                                                    nullptr, h,
                                                    ln_g + (size_t)l * 128,
                                                    ln_b + (size_t)l * 128, h, hbf, N);
    }

    // ---- FFN head
    ffn_mfma<<<(N + 63) / 64, 256, 0, stream>>>(hbf, f1T, f1b, f2T, f2b, f3T, f3b,
                                                (float*)d_out, N);
}

// Round 3
// 612.318 us; speedup vs baseline: 2.6075x; 1.1889x over previous
//
#include <hip/hip_runtime.h>
#include <hip/hip_bf16.h>
#include <math.h>

// ---------------------------------------------------------------------------
// GraphMemoryNetwork — Round 2: occupancy-fixed FFN, vectorized attention,
// multi-block scan, batched transposes.
// N=50000, E=640000, D_IN=256, D=128, H=8, DH=16, NC=47, L=3
// ---------------------------------------------------------------------------

typedef __bf16 bf16x8 __attribute__((ext_vector_type(8)));
typedef __bf16 bf16x4 __attribute__((ext_vector_type(4)));
typedef __bf16 bf16x2 __attribute__((ext_vector_type(2)));
typedef float  f32x4  __attribute__((ext_vector_type(4)));

#define MFMA16(a, b, c) __builtin_amdgcn_mfma_f32_16x16x32_bf16((a), (b), (c), 0, 0, 0)

// ------------------------- CSR build ---------------------------------------

__global__ __launch_bounds__(256) void zero_ints(int* __restrict__ p, int n) {
    int i = blockIdx.x * 256 + threadIdx.x;
    if (i < n) p[i] = 0;
}

__global__ __launch_bounds__(256) void count_deg(const int* __restrict__ ei,
                                                 int* __restrict__ deg, int E) {
    int e = blockIdx.x * 256 + threadIdx.x;
    if (e < E) atomicAdd(&deg[ei[(size_t)E + e]], 1);   // dst = ei[1][e]
}

// block b sums deg[b*1024 .. b*1024+1024) -> partials[b]
__global__ __launch_bounds__(256) void scan_part(const int* __restrict__ deg,
                                                 int* __restrict__ partials, int N) {
    int b = blockIdx.x, t = threadIdx.x, lane = t & 63, w = t >> 6;
    int base = b * 1024 + t * 4;
    int4 v = make_int4(0, 0, 0, 0);
    if (base + 3 < N) v = *(const int4*)&deg[base];
    else {
        if (base < N)     v.x = deg[base];
        if (base + 1 < N) v.y = deg[base + 1];
        if (base + 2 < N) v.z = deg[base + 2];
    }
    int s = v.x + v.y + v.z + v.w;
#pragma unroll
    for (int o = 1; o < 64; o <<= 1) s += __shfl_xor(s, o);
    __shared__ int ws[4];
    if (lane == 0) ws[w] = s;
    __syncthreads();
    if (t == 0) partials[b] = ws[0] + ws[1] + ws[2] + ws[3];
}

// single wave: exclusive-scan partials[0..nb), write total to row_ptr[N]
__global__ __launch_bounds__(64) void scan_mid(int* __restrict__ partials,
                                               int* __restrict__ row_ptr,
                                               int nb, int N) {
    int t = threadIdx.x;
    int v = (t < nb) ? partials[t] : 0;
    int incl = v;
#pragma unroll
    for (int o = 1; o < 64; o <<= 1) {
        int u = __shfl_up(incl, o);
        if (t >= o) incl += u;
    }
    if (t < nb) partials[t] = incl - v;
    if (t == nb - 1) row_ptr[N] = incl;
}

__global__ __launch_bounds__(256) void scan_final(const int* __restrict__ deg,
                                                  const int* __restrict__ partials,
                                                  int* __restrict__ row_ptr, int N) {
    int b = blockIdx.x, t = threadIdx.x, lane = t & 63, w = t >> 6;
    int base = b * 1024 + t * 4;
    int4 v = make_int4(0, 0, 0, 0);
    if (base + 3 < N) v = *(const int4*)&deg[base];
    else {
        if (base < N)     v.x = deg[base];
        if (base + 1 < N) v.y = deg[base + 1];
        if (base + 2 < N) v.z = deg[base + 2];
    }
    int c1 = v.x, c2 = c1 + v.y, c3 = c2 + v.z, c4 = c3 + v.w;
    int s = c4, incl = s;
#pragma unroll
    for (int o = 1; o < 64; o <<= 1) {
        int u = __shfl_up(incl, o);
        if (lane >= o) incl += u;
    }
    int texcl = incl - s;
    __shared__ int ws[4];
    if (lane == 63) ws[w] = incl;
    __syncthreads();
    int woff = 0;
    for (int i = 0; i < w; ++i) woff += ws[i];
    int off = partials[b] + woff + texcl;
    if (base < N)     row_ptr[base]     = off;
    if (base + 1 < N) row_ptr[base + 1] = off + c1;
    if (base + 2 < N) row_ptr[base + 2] = off + c2;
    if (base + 3 < N) row_ptr[base + 3] = off + c3;
}

__global__ __launch_bounds__(256) void scatter_edges(const int* __restrict__ ei,
                                                     const int* __restrict__ row_ptr,
                                                     int* __restrict__ cursor,
                                                     int* __restrict__ csr_src, int E) {
    int e = blockIdx.x * 256 + threadIdx.x;
    if (e < E) {
        int d = ei[(size_t)E + e];
        int pos = row_ptr[d] + atomicAdd(&cursor[d], 1);
        csr_src[pos] = ei[e];
    }
}

// ------------------------- batched weight transpose -------------------------
// out[n][k] = (bf16) in[k][n]. One launch for all 14 weight matrices.
// Tile map (32x32 tiles): [0,32) emb | [32,96) f1 | [96,352) f2 | [352,384) f3
// | [384,576) the 12 layer matrices (Wq,Wk,Wv,Wo per layer).

__global__ __launch_bounds__(256) void transpose_all(
    const float* __restrict__ emb_w, const float* __restrict__ f1w,
    const float* __restrict__ f2w, const float* __restrict__ f3w,
    const float* __restrict__ Wq, const float* __restrict__ Wk,
    const float* __restrict__ Wv, const float* __restrict__ Wo,
    __bf16* __restrict__ embT, __bf16* __restrict__ f1T,
    __bf16* __restrict__ f2T, __bf16* __restrict__ f3T,
    __bf16* __restrict__ qkvT, __bf16* __restrict__ woT) {
    __shared__ float tile[32][33];
    int t = blockIdx.x;
    const float* src; __bf16* dst; int K, Nin, Npad, nxt;
    if (t < 32)       { src = emb_w; dst = embT; K = 256; Nin = 128; Npad = 128; nxt = 4; }
    else if (t < 96)  { t -= 32;  src = f1w; dst = f1T; K = 128; Nin = 512; Npad = 512; nxt = 16; }
    else if (t < 352) { t -= 96;  src = f2w; dst = f2T; K = 512; Nin = 512; Npad = 512; nxt = 16; }
    else if (t < 384) { t -= 352; src = f3w; dst = f3T; K = 512; Nin = 47;  Npad = 48;  nxt = 2; }
    else {
        t -= 384;
        int mat = t >> 4; t &= 15;
        int l = mat >> 2, m = mat & 3;
        src = (m == 0 ? Wq : m == 1 ? Wk : m == 2 ? Wv : Wo) + (size_t)l * 16384;
        dst = (m < 3) ? qkvT + (size_t)l * 49152 + (size_t)m * 16384
                      : woT + (size_t)l * 16384;
        K = 128; Nin = 128; Npad = 128; nxt = 4;
    }
    int n0 = (t % nxt) * 32, k0 = (t / nxt) * 32;
    int tx = threadIdx.x & 31, ty = threadIdx.x >> 5;
#pragma unroll
    for (int i = 0; i < 32; i += 8) {
        int k = k0 + ty + i, n = n0 + tx;
        tile[ty + i][tx] = (k < K && n < Nin) ? src[(size_t)k * Nin + n] : 0.f;
    }
    __syncthreads();
#pragma unroll
    for (int i = 0; i < 32; i += 8) {
        int n = n0 + ty + i, k = k0 + tx;
        if (n < Npad && k < K) dst[(size_t)n * K + k] = (__bf16)tile[tx][ty + i];
    }
}

// ------------------------- plain MFMA GEMM (C bf16) -------------------------
// MT m-tiles (16 rows each) per wave; full Nmat width. No LDS, no barriers.

template <int K, int NTILES, int MT>
__global__ __launch_bounds__(256) void gemm_bf16(const __bf16* __restrict__ A,
                                                 const __bf16* __restrict__ BT,
                                                 __bf16* __restrict__ C, int M) {
    int wid = (blockIdx.x * 256 + threadIdx.x) >> 6;
    int lane = threadIdx.x & 63;
    int m0 = wid * 16 * MT;
    if (m0 >= M) return;
    constexpr int KS = K / 32;
    constexpr int NMAT = NTILES * 16;
    int cb = lane & 15;
    int kc = (lane >> 4) * 8;
    int rq = (lane >> 4) * 4;

    bf16x8 a[MT][KS];
#pragma unroll
    for (int mt = 0; mt < MT; ++mt) {
        int row = m0 + mt * 16 + cb;
        if (row >= M) row = M - 1;
#pragma unroll
        for (int ks = 0; ks < KS; ++ks)
            a[mt][ks] = *(const bf16x8*)&A[(size_t)row * K + ks * 32 + kc];
    }

#pragma unroll
    for (int nt = 0; nt < NTILES; ++nt) {
        f32x4 acc[MT];
#pragma unroll
        for (int mt = 0; mt < MT; ++mt) acc[mt] = (f32x4){0.f, 0.f, 0.f, 0.f};
        const __bf16* bp = &BT[(size_t)(nt * 16 + cb) * K + kc];
#pragma unroll
        for (int ks = 0; ks < KS; ++ks) {
            bf16x8 b = *(const bf16x8*)&bp[ks * 32];
#pragma unroll
            for (int mt = 0; mt < MT; ++mt) acc[mt] = MFMA16(a[mt][ks], b, acc[mt]);
        }
        int col = nt * 16 + cb;
#pragma unroll
        for (int mt = 0; mt < MT; ++mt)
#pragma unroll
            for (int i = 0; i < 4; ++i) {
                int row = m0 + mt * 16 + rq + i;
                if (row < M) C[(size_t)row * NMAT + col] = (__bf16)acc[mt][i];
            }
    }
}

// ------------------------- MFMA GEMM + fused LayerNorm ----------------------
// Nmat = 128 (full row per wave). EMB: A is fp32, y = LN(relu(A@B + bias));
// else A bf16, y = LN(resid + A@B). Writes fp32 hout and bf16 hbf.

template <int K, bool EMB>
__global__ __launch_bounds__(256) void gemm_ln(const void* __restrict__ Av,
                                               const __bf16* __restrict__ BT,
                                               const float* __restrict__ bias,
                                               const float* resid,
                                               const float* __restrict__ g,
                                               const float* __restrict__ beta,
                                               float* hout, __bf16* __restrict__ hbf,
                                               int M) {
    int wid = (blockIdx.x * 256 + threadIdx.x) >> 6;
    int lane = threadIdx.x & 63;
    int m0 = wid * 16;
    if (m0 >= M) return;
    constexpr int KS = K / 32;
    int cb = lane & 15;
    int kc = (lane >> 4) * 8;
    int rq = (lane >> 4) * 4;
    int arow = m0 + cb;
    if (arow >= M) arow = M - 1;

    bf16x8 a[KS];
    if constexpr (EMB) {
        const float* A = (const float*)Av;
#pragma unroll
        for (int ks = 0; ks < KS; ++ks) {
            float4 u0 = *(const float4*)&A[(size_t)arow * K + ks * 32 + kc];
            float4 u1 = *(const float4*)&A[(size_t)arow * K + ks * 32 + kc + 4];
            bf16x8 av;
            av[0] = (__bf16)u0.x; av[1] = (__bf16)u0.y; av[2] = (__bf16)u0.z; av[3] = (__bf16)u0.w;
            av[4] = (__bf16)u1.x; av[5] = (__bf16)u1.y; av[6] = (__bf16)u1.z; av[7] = (__bf16)u1.w;
            a[ks] = av;
        }
    } else {
        const __bf16* A = (const __bf16*)Av;
#pragma unroll
        for (int ks = 0; ks < KS; ++ks)
            a[ks] = *(const bf16x8*)&A[(size_t)arow * K + ks * 32 + kc];
    }

    f32x4 acc[8];
#pragma unroll
    for (int nt = 0; nt < 8; ++nt) acc[nt] = (f32x4){0.f, 0.f, 0.f, 0.f};
#pragma unroll
    for (int nt = 0; nt < 8; ++nt) {
        const __bf16* bp = &BT[(size_t)(nt * 16 + cb) * K + kc];
#pragma unroll
        for (int ks = 0; ks < KS; ++ks) {
            bf16x8 b = *(const bf16x8*)&bp[ks * 32];
            acc[nt] = MFMA16(a[ks], b, acc[nt]);
        }
    }

#pragma unroll
    for (int nt = 0; nt < 8; ++nt) {
        int col = nt * 16 + cb;
        float bb = EMB ? bias[col] : 0.f;
#pragma unroll
        for (int i = 0; i < 4; ++i) {
            float v = acc[nt][i];
            if (EMB) {
                v = fmaxf(v + bb, 0.f);
            } else {
                int row = m0 + rq + i;
                if (row >= M) row = M - 1;
                v += resid[(size_t)row * 128 + col];
            }
            acc[nt][i] = v;
        }
    }

    float s[4] = {0.f, 0.f, 0.f, 0.f}, qs[4] = {0.f, 0.f, 0.f, 0.f};
#pragma unroll
    for (int nt = 0; nt < 8; ++nt)
#pragma unroll
        for (int i = 0; i < 4; ++i) {
            float v = acc[nt][i];
            s[i] += v;
            qs[i] += v * v;
        }
#pragma unroll
    for (int i = 0; i < 4; ++i)
#pragma unroll
        for (int o = 1; o < 16; o <<= 1) {
            s[i] += __shfl_xor(s[i], o);
            qs[i] += __shfl_xor(qs[i], o);
        }
    float mu[4], rstd[4];
#pragma unroll
    for (int i = 0; i < 4; ++i) {
        mu[i] = s[i] * (1.f / 128.f);
        float var = qs[i] * (1.f / 128.f) - mu[i] * mu[i];
        rstd[i] = rsqrtf(var + 1e-5f);
    }

#pragma unroll
    for (int nt = 0; nt < 8; ++nt) {
        int col = nt * 16 + cb;
        float gv = g[col], bv = beta[col];
#pragma unroll
        for (int i = 0; i < 4; ++i) {
            int row = m0 + rq + i;
            if (row >= M) continue;
            float y = (acc[nt][i] - mu[i]) * rstd[i] * gv + bv;
            size_t idx = (size_t)row * 128 + col;
            hout[idx] = y;
            hbf[idx] = (__bf16)y;
        }
    }
}

// ------------------------- attention (16 lanes x 4 edge slots) --------------
// One wave per dst node. Lane layout: slot j = lane>>4 (edge), q16 = lane&15,
// channels c0 = q16*8 (bf16x8 = 16B loads). Head = q16>>1 (16ch = 2 lanes).
// 4 independent online-softmax streams merged at the end.

__global__ __launch_bounds__(256) void attn_gat(const __bf16* __restrict__ qkv,
                                                const int* __restrict__ row_ptr,
                                                const int* __restrict__ csr_src,
                                                __bf16* __restrict__ agg, int N) {
    int wave = threadIdx.x >> 6;
    int lane = threadIdx.x & 63;
    int n = blockIdx.x * 4 + wave;
    if (n >= N) return;
    int j = lane >> 4, q16 = lane & 15, c0 = q16 * 8;
    const float scale = 0.25f;  // 1/sqrt(16)

    bf16x8 qv = *(const bf16x8*)&qkv[(size_t)n * 384 + c0];
    float qf[8];
#pragma unroll
    for (int i = 0; i < 8; ++i) qf[i] = (float)qv[i];

    int e0 = row_ptr[n], e1 = row_ptr[n + 1];
    float m = -3e38f, s = 0.f;
    float acc[8] = {0.f, 0.f, 0.f, 0.f, 0.f, 0.f, 0.f, 0.f};

    for (int base = e0; base < e1; base += 4) {
        int e = base + j;
        bool valid = e < e1;
        int src = csr_src[valid ? e : e0];
        const __bf16* kp = &qkv[(size_t)src * 384 + 128 + c0];
        bf16x8 kv = *(const bf16x8*)kp;
        bf16x8 vv = *(const bf16x8*)(kp + 128);
        float d = 0.f;
#pragma unroll
        for (int i = 0; i < 8; ++i) d = fmaf(qf[i], (float)kv[i], d);
        d += __shfl_xor(d, 1);          // pair lanes -> full 16-ch head dot
        float sc = d * scale;
        if (valid) {
            float mn = fmaxf(m, sc);
            float f = __expf(m - mn), p = __expf(sc - mn);
            s = s * f + p;
#pragma unroll
            for (int i = 0; i < 8; ++i) acc[i] = acc[i] * f + p * (float)vv[i];
            m = mn;
        }
    }

    // merge 4 slots (lane bits 4 and 5)
#pragma unroll
    for (int off = 16; off <= 32; off <<= 1) {
        float mo_ = __shfl_xor(m, off);
        float so_ = __shfl_xor(s, off);
        float mn = fmaxf(m, mo_);
        float f = __expf(m - mn), fo = __expf(mo_ - mn);
        s = s * f + so_ * fo;
#pragma unroll
        for (int i = 0; i < 8; ++i)
            acc[i] = acc[i] * f + __shfl_xor(acc[i], off) * fo;
        m = mn;
    }

    if (j == 0) {
        float inv = (s > 0.f) ? 1.f / s : 0.f;
        bf16x8 o;
#pragma unroll
        for (int i = 0; i < 8; ++i) o[i] = (__bf16)(acc[i] * inv);
        *(bf16x8*)&agg[(size_t)n * 128 + c0] = o;
    }
}

// ------------------------- FFN head (MFMA, 3 phases) ------------------------
// Block = 512 threads (8 waves), 32 rows. Wave w owns cols [w*64, w*64+64).
// h[32][128] -> h1[32][512] (LDS, XOR-swizzled) -> h2 (same LDS) -> out[32][47].
// LDS 32KB; launch_bounds(512,4) caps VGPR at 128 -> 2 blocks/CU (16 waves).

__global__ __launch_bounds__(512, 4) void ffn_mfma(const __bf16* __restrict__ hbf,
                                                   const __bf16* __restrict__ f1T,
                                                   const float* __restrict__ f1b,
                                                   const __bf16* __restrict__ f2T,
                                                   const float* __restrict__ f2b,
                                                   const __bf16* __restrict__ f3T,
                                                   const float* __restrict__ f3b,
                                                   float* __restrict__ out, int M) {
    __shared__ __bf16 hbuf[32 * 512];  // byte = rl*1024 + col*2, ^((rl&7)<<4)
    int w = threadIdx.x >> 6;
    int lane = threadIdx.x & 63;
    int r0 = blockIdx.x * 32;
    int cb = lane & 15;
    int kc = (lane >> 4) * 8;
    int rq = (lane >> 4) * 4;
    char* hb = (char*)hbuf;

    // ---- phase 1: h1 = relu(h @ f1w + b1); 2 m-tiles, 4 n-tiles per wave
    {
        bf16x8 a1[2][4];
#pragma unroll
        for (int mt = 0; mt < 2; ++mt) {
            int row = r0 + mt * 16 + cb;
            if (row >= M) row = M - 1;
#pragma unroll
            for (int ks = 0; ks < 4; ++ks)
                a1[mt][ks] = *(const bf16x8*)&hbf[(size_t)row * 128 + ks * 32 + kc];
        }
#pragma unroll
        for (int nt = 0; nt < 4; ++nt) {
            int ncol = w * 64 + nt * 16;
            f32x4 acc[2];
            acc[0] = (f32x4){0.f, 0.f, 0.f, 0.f};
            acc[1] = (f32x4){0.f, 0.f, 0.f, 0.f};
            const __bf16* bp = &f1T[(size_t)(ncol + cb) * 128 + kc];
#pragma unroll
            for (int ks = 0; ks < 4; ++ks) {
                bf16x8 b = *(const bf16x8*)&bp[ks * 32];
                acc[0] = MFMA16(a1[0][ks], b, acc[0]);
                acc[1] = MFMA16(a1[1][ks], b, acc[1]);
            }
            float bb = f1b[ncol + cb];
#pragma unroll
            for (int mt = 0; mt < 2; ++mt)
#pragma unroll
                for (int i = 0; i < 4; ++i) {
                    int rl = mt * 16 + rq + i;
                    int byte = (rl * 1024 + (ncol + cb) * 2) ^ ((rl & 7) << 4);
                    *(__bf16*)(hb + byte) = (__bf16)fmaxf(acc[mt][i] + bb, 0.f);
                }
        }
    }
    __syncthreads();

    // ---- phase 2: h2 = relu(h1 @ f2w + b2); K=512, double-buffered B
    f32x4 acc2[2][4];
#pragma unroll
    for (int mt = 0; mt < 2; ++mt)
#pragma unroll
        for (int nt = 0; nt < 4; ++nt) acc2[mt][nt] = (f32x4){0.f, 0.f, 0.f, 0.f};

    const __bf16* bpn[4];
#pragma unroll
    for (int nt = 0; nt < 4; ++nt)
        bpn[nt] = &f2T[(size_t)(w * 64 + nt * 16 + cb) * 512 + kc];

    bf16x8 bcur[4];
#pragma unroll
    for (int nt = 0; nt < 4; ++nt) bcur[nt] = *(const bf16x8*)bpn[nt];

    for (int ks = 0; ks < 16; ++ks) {
        bf16x8 a2[2];
#pragma unroll
        for (int mt = 0; mt < 2; ++mt) {
            int rl = mt * 16 + cb;
            int byte = (rl * 1024 + (ks * 32 + kc) * 2) ^ ((rl & 7) << 4);
            a2[mt] = *(const bf16x8*)(hb + byte);
        }
        bf16x8 bnext[4];
        if (ks < 15) {
#pragma unroll
            for (int nt = 0; nt < 4; ++nt)
                bnext[nt] = *(const bf16x8*)(bpn[nt] + (ks + 1) * 32);
        }
#pragma unroll
        for (int nt = 0; nt < 4; ++nt) {
            acc2[0][nt] = MFMA16(a2[0], bcur[nt], acc2[0][nt]);
            acc2[1][nt] = MFMA16(a2[1], bcur[nt], acc2[1][nt]);
        }
#pragma unroll
        for (int nt = 0; nt < 4; ++nt) bcur[nt] = bnext[nt];
    }
    __syncthreads();  // all h1 reads done before overwrite
#pragma unroll
    for (int nt = 0; nt < 4; ++nt) {
        int ncol = w * 64 + nt * 16;
        float bb = f2b[ncol + cb];
#pragma unroll
        for (int mt = 0; mt < 2; ++mt)
#pragma unroll
            for (int i = 0; i < 4; ++i) {
                int rl = mt * 16 + rq + i;
                int byte = (rl * 1024 + (ncol + cb) * 2) ^ ((rl & 7) << 4);
                *(__bf16*)(hb + byte) = (__bf16)fmaxf(acc2[mt][nt][i] + bb, 0.f);
            }
    }
    __syncthreads();

    // ---- phase 3: out = h2 @ f3w + b3; 6 tile-jobs over waves 0..5
    if (w < 6) {
        int mt = w & 1, nt = w >> 1;  // nt in 0..2
        f32x4 acc3 = (f32x4){0.f, 0.f, 0.f, 0.f};
        const __bf16* bp = &f3T[(size_t)(nt * 16 + cb) * 512 + kc];
        for (int ks = 0; ks < 16; ++ks) {
            int rl = mt * 16 + cb;
            int byte = (rl * 1024 + (ks * 32 + kc) * 2) ^ ((rl & 7) << 4);
            bf16x8 a3 = *(const bf16x8*)(hb + byte);
            bf16x8 b = *(const bf16x8*)(bp + ks * 32);
            acc3 = MFMA16(a3, b, acc3);
        }
        int col = nt * 16 + cb;
        if (col < 47) {
            float bb = f3b[col];
            int r = r0 + mt * 16 + rq;
#pragma unroll
            for (int i = 0; i < 4; ++i)
                if (r + i < M) out[(size_t)(r + i) * 47 + col] = acc3[i] + bb;
        }
    }
}

// ------------------------- launch -------------------------------------------

extern "C" void kernel_launch(void* const* d_in, const int* in_sizes, int n_in,
                              void* d_out, int out_size, void* d_ws, size_t ws_size,
                              hipStream_t stream) {
    const float* X        = (const float*)d_in[0];
    const int*   ei       = (const int*)d_in[1];
    const float* emb_w    = (const float*)d_in[2];
    const float* emb_b    = (const float*)d_in[3];
    const float* emb_ln_g = (const float*)d_in[4];
    const float* emb_ln_b = (const float*)d_in[5];
    const float* Wq       = (const float*)d_in[6];
    const float* Wk       = (const float*)d_in[7];
    const float* Wv       = (const float*)d_in[8];
    const float* Wo       = (const float*)d_in[9];
    const float* ln_g     = (const float*)d_in[10];
    const float* ln_b     = (const float*)d_in[11];
    const float* f1w      = (const float*)d_in[12];
    const float* f1b      = (const float*)d_in[13];
    const float* f2w      = (const float*)d_in[14];
    const float* f2b      = (const float*)d_in[15];
    const float* f3w      = (const float*)d_in[16];
    const float* f3b      = (const float*)d_in[17];

    const int N = in_sizes[0] / 256;  // 50000
    const int E = in_sizes[1] / 2;    // 640000
    const int NB = (N + 1023) / 1024; // scan blocks (49)

    // ---- workspace layout
    char* p = (char*)d_ws;
    float* h = (float*)p;            p += (size_t)N * 128 * 4;
    __bf16* hbf = (__bf16*)p;        p += (size_t)N * 128 * 2;
    __bf16* qkv = (__bf16*)p;        p += (size_t)N * 384 * 2;
    __bf16* aggb = (__bf16*)p;       p += (size_t)N * 128 * 2;
    __bf16* embT = (__bf16*)p;       p += 128 * 256 * 2;
    __bf16* qkvT = (__bf16*)p;       p += 3 * 384 * 128 * 2;
    __bf16* woT = (__bf16*)p;        p += 3 * 128 * 128 * 2;
    __bf16* f1T = (__bf16*)p;        p += 512 * 128 * 2;
    __bf16* f2T = (__bf16*)p;        p += 512 * 512 * 2;
    __bf16* f3T = (__bf16*)p;        p += 48 * 512 * 2;
    int* deg = (int*)p;              p += (size_t)N * 4;
    int* cursor = (int*)p;           p += (size_t)N * 4;
    int* row_ptr = (int*)p;          p += (size_t)(N + 1) * 4;
    int* csr_src = (int*)p;          p += (size_t)E * 4;
    int* partials = (int*)p;

    // ---- CSR build
    zero_ints<<<(2 * N + 255) / 256, 256, 0, stream>>>(deg, 2 * N);
    count_deg<<<(E + 255) / 256, 256, 0, stream>>>(ei, deg, E);
    scan_part<<<NB, 256, 0, stream>>>(deg, partials, N);
    scan_mid<<<1, 64, 0, stream>>>(partials, row_ptr, NB, N);
    scan_final<<<NB, 256, 0, stream>>>(deg, partials, row_ptr, N);
    scatter_edges<<<(E + 255) / 256, 256, 0, stream>>>(ei, row_ptr, cursor, csr_src, E);

    // ---- all weight transposes in one launch
    transpose_all<<<576, 256, 0, stream>>>(emb_w, f1w, f2w, f3w, Wq, Wk, Wv, Wo,
                                           embT, f1T, f2T, f3T, qkvT, woT);

    int gw16 = ((N + 15) / 16 + 3) / 4;   // 1 wave / 16 rows, 4 waves/block
    int gw32 = ((N + 31) / 32 + 3) / 4;   // 1 wave / 32 rows

    // ---- embedding: LN(relu(X @ emb_w + emb_b)) -> h (fp32) + hbf
    gemm_ln<256, true><<<gw16, 256, 0, stream>>>(X, embT, emb_b, nullptr,
                                                 emb_ln_g, emb_ln_b, h, hbf, N);

    // ---- layers
    for (int l = 0; l < 3; ++l) {
        gemm_bf16<128, 24, 2><<<gw32, 256, 0, stream>>>(hbf, qkvT + (size_t)l * 49152,
                                                        qkv, N);
        attn_gat<<<(N + 3) / 4, 256, 0, stream>>>(qkv, row_ptr, csr_src, aggb, N);
        gemm_ln<128, false><<<gw16, 256, 0, stream>>>(aggb, woT + (size_t)l * 16384,
                                                      nullptr, h,
                                                      ln_g + (size_t)l * 128,
                                                      ln_b + (size_t)l * 128, h, hbf, N);
    }

    // ---- FFN head
    ffn_mfma<<<(N + 31) / 32, 512, 0, stream>>>(hbf, f1T, f1b, f2T, f2b, f3T, f3b,
                                                (float*)d_out, N);
}

// Round 4
// 593.666 us; speedup vs baseline: 2.6894x; 1.0314x over previous
//
#include <hip/hip_runtime.h>
#include <hip/hip_bf16.h>
#include <math.h>

// ---------------------------------------------------------------------------
// GraphMemoryNetwork — Round 3: deep-prefetch streaming MFMA GEMMs.
// N=50000, E=640000, D_IN=256, D=128, H=8, DH=16, NC=47, L=3
// ---------------------------------------------------------------------------

typedef __bf16 bf16x8 __attribute__((ext_vector_type(8)));
typedef __bf16 bf16x4 __attribute__((ext_vector_type(4)));
typedef __bf16 bf16x2 __attribute__((ext_vector_type(2)));
typedef float  f32x4  __attribute__((ext_vector_type(4)));

#define MFMA16(a, b, c) __builtin_amdgcn_mfma_f32_16x16x32_bf16((a), (b), (c), 0, 0, 0)

// ------------------------- CSR build ---------------------------------------

__global__ __launch_bounds__(256) void zero_ints(int* __restrict__ p, int n) {
    int i = blockIdx.x * 256 + threadIdx.x;
    if (i < n) p[i] = 0;
}

__global__ __launch_bounds__(256) void count_deg(const int* __restrict__ ei,
                                                 int* __restrict__ deg, int E) {
    int e = blockIdx.x * 256 + threadIdx.x;
    if (e < E) atomicAdd(&deg[ei[(size_t)E + e]], 1);   // dst = ei[1][e]
}

__global__ __launch_bounds__(256) void scan_part(const int* __restrict__ deg,
                                                 int* __restrict__ partials, int N) {
    int b = blockIdx.x, t = threadIdx.x, lane = t & 63, w = t >> 6;
    int base = b * 1024 + t * 4;
    int4 v = make_int4(0, 0, 0, 0);
    if (base + 3 < N) v = *(const int4*)&deg[base];
    else {
        if (base < N)     v.x = deg[base];
        if (base + 1 < N) v.y = deg[base + 1];
        if (base + 2 < N) v.z = deg[base + 2];
    }
    int s = v.x + v.y + v.z + v.w;
#pragma unroll
    for (int o = 1; o < 64; o <<= 1) s += __shfl_xor(s, o);
    __shared__ int ws[4];
    if (lane == 0) ws[w] = s;
    __syncthreads();
    if (t == 0) partials[b] = ws[0] + ws[1] + ws[2] + ws[3];
}

__global__ __launch_bounds__(64) void scan_mid(int* __restrict__ partials,
                                               int* __restrict__ row_ptr,
                                               int nb, int N) {
    int t = threadIdx.x;
    int v = (t < nb) ? partials[t] : 0;
    int incl = v;
#pragma unroll
    for (int o = 1; o < 64; o <<= 1) {
        int u = __shfl_up(incl, o);
        if (t >= o) incl += u;
    }
    if (t < nb) partials[t] = incl - v;
    if (t == nb - 1) row_ptr[N] = incl;
}

__global__ __launch_bounds__(256) void scan_final(const int* __restrict__ deg,
                                                  const int* __restrict__ partials,
                                                  int* __restrict__ row_ptr, int N) {
    int b = blockIdx.x, t = threadIdx.x, lane = t & 63, w = t >> 6;
    int base = b * 1024 + t * 4;
    int4 v = make_int4(0, 0, 0, 0);
    if (base + 3 < N) v = *(const int4*)&deg[base];
    else {
        if (base < N)     v.x = deg[base];
        if (base + 1 < N) v.y = deg[base + 1];
        if (base + 2 < N) v.z = deg[base + 2];
    }
    int c1 = v.x, c2 = c1 + v.y, c3 = c2 + v.z, c4 = c3 + v.w;
    int s = c4, incl = s;
#pragma unroll
    for (int o = 1; o < 64; o <<= 1) {
        int u = __shfl_up(incl, o);
        if (lane >= o) incl += u;
    }
    int texcl = incl - s;
    __shared__ int ws[4];
    if (lane == 63) ws[w] = incl;
    __syncthreads();
    int woff = 0;
    for (int i = 0; i < w; ++i) woff += ws[i];
    int off = partials[b] + woff + texcl;
    if (base < N)     row_ptr[base]     = off;
    if (base + 1 < N) row_ptr[base + 1] = off + c1;
    if (base + 2 < N) row_ptr[base + 2] = off + c2;
    if (base + 3 < N) row_ptr[base + 3] = off + c3;
}

__global__ __launch_bounds__(256) void scatter_edges(const int* __restrict__ ei,
                                                     const int* __restrict__ row_ptr,
                                                     int* __restrict__ cursor,
                                                     int* __restrict__ csr_src, int E) {
    int e = blockIdx.x * 256 + threadIdx.x;
    if (e < E) {
        int d = ei[(size_t)E + e];
        int pos = row_ptr[d] + atomicAdd(&cursor[d], 1);
        csr_src[pos] = ei[e];
    }
}

// ------------------------- batched weight transpose -------------------------

__global__ __launch_bounds__(256) void transpose_all(
    const float* __restrict__ emb_w, const float* __restrict__ f1w,
    const float* __restrict__ f2w, const float* __restrict__ f3w,
    const float* __restrict__ Wq, const float* __restrict__ Wk,
    const float* __restrict__ Wv, const float* __restrict__ Wo,
    __bf16* __restrict__ embT, __bf16* __restrict__ f1T,
    __bf16* __restrict__ f2T, __bf16* __restrict__ f3T,
    __bf16* __restrict__ qkvT, __bf16* __restrict__ woT) {
    __shared__ float tile[32][33];
    int t = blockIdx.x;
    const float* src; __bf16* dst; int K, Nin, Npad, nxt;
    if (t < 32)       { src = emb_w; dst = embT; K = 256; Nin = 128; Npad = 128; nxt = 4; }
    else if (t < 96)  { t -= 32;  src = f1w; dst = f1T; K = 128; Nin = 512; Npad = 512; nxt = 16; }
    else if (t < 352) { t -= 96;  src = f2w; dst = f2T; K = 512; Nin = 512; Npad = 512; nxt = 16; }
    else if (t < 384) { t -= 352; src = f3w; dst = f3T; K = 512; Nin = 47;  Npad = 48;  nxt = 2; }
    else {
        t -= 384;
        int mat = t >> 4; t &= 15;
        int l = mat >> 2, m = mat & 3;
        src = (m == 0 ? Wq : m == 1 ? Wk : m == 2 ? Wv : Wo) + (size_t)l * 16384;
        dst = (m < 3) ? qkvT + (size_t)l * 49152 + (size_t)m * 16384
                      : woT + (size_t)l * 16384;
        K = 128; Nin = 128; Npad = 128; nxt = 4;
    }
    int n0 = (t % nxt) * 32, k0 = (t / nxt) * 32;
    int tx = threadIdx.x & 31, ty = threadIdx.x >> 5;
#pragma unroll
    for (int i = 0; i < 32; i += 8) {
        int k = k0 + ty + i, n = n0 + tx;
        tile[ty + i][tx] = (k < K && n < Nin) ? src[(size_t)k * Nin + n] : 0.f;
    }
    __syncthreads();
#pragma unroll
    for (int i = 0; i < 32; i += 8) {
        int n = n0 + ty + i, k = k0 + tx;
        if (n < Npad && k < K) dst[(size_t)n * K + k] = (__bf16)tile[tx][ty + i];
    }
}

// ------------------------- streaming MFMA GEMM (C bf16) ---------------------
// MT m-tiles (16 rows) per wave, full Nmat width, B double-buffered one
// n-tile ahead (parity buffers, no register copies).

template <int K, int NTILES, int MT>
__global__ __launch_bounds__(256) void gemm_bf16(const __bf16* __restrict__ A,
                                                 const __bf16* __restrict__ BT,
                                                 __bf16* __restrict__ C, int M) {
    int wid = (blockIdx.x * 256 + threadIdx.x) >> 6;
    int lane = threadIdx.x & 63;
    int m0 = wid * 16 * MT;
    if (m0 >= M) return;
    constexpr int KS = K / 32;
    constexpr int NMAT = NTILES * 16;
    int cb = lane & 15;
    int kc = (lane >> 4) * 8;
    int rq = (lane >> 4) * 4;

    bf16x8 a[MT][KS];
#pragma unroll
    for (int mt = 0; mt < MT; ++mt) {
        int row = m0 + mt * 16 + cb;
        if (row >= M) row = M - 1;
#pragma unroll
        for (int ks = 0; ks < KS; ++ks)
            a[mt][ks] = *(const bf16x8*)&A[(size_t)row * K + ks * 32 + kc];
    }

    const __bf16* bbase = &BT[(size_t)cb * K + kc];
    bf16x8 bA[KS], bB[KS];
#pragma unroll
    for (int ks = 0; ks < KS; ++ks) bA[ks] = *(const bf16x8*)(bbase + ks * 32);

#pragma unroll
    for (int nt = 0; nt < NTILES; nt += 2) {
        // prefetch nt+1
#pragma unroll
        for (int ks = 0; ks < KS; ++ks)
            bB[ks] = *(const bf16x8*)(bbase + (size_t)(nt + 1) * 16 * K + ks * 32);
        {
            f32x4 acc[MT];
#pragma unroll
            for (int mt = 0; mt < MT; ++mt) acc[mt] = (f32x4){0.f, 0.f, 0.f, 0.f};
#pragma unroll
            for (int ks = 0; ks < KS; ++ks)
#pragma unroll
                for (int mt = 0; mt < MT; ++mt) acc[mt] = MFMA16(a[mt][ks], bA[ks], acc[mt]);
            int col = nt * 16 + cb;
#pragma unroll
            for (int mt = 0; mt < MT; ++mt)
#pragma unroll
                for (int i = 0; i < 4; ++i) {
                    int row = m0 + mt * 16 + rq + i;
                    if (row < M) C[(size_t)row * NMAT + col] = (__bf16)acc[mt][i];
                }
        }
        // prefetch nt+2
        if (nt + 2 < NTILES) {
#pragma unroll
            for (int ks = 0; ks < KS; ++ks)
                bA[ks] = *(const bf16x8*)(bbase + (size_t)(nt + 2) * 16 * K + ks * 32);
        }
        {
            f32x4 acc[MT];
#pragma unroll
            for (int mt = 0; mt < MT; ++mt) acc[mt] = (f32x4){0.f, 0.f, 0.f, 0.f};
#pragma unroll
            for (int ks = 0; ks < KS; ++ks)
#pragma unroll
                for (int mt = 0; mt < MT; ++mt) acc[mt] = MFMA16(a[mt][ks], bB[ks], acc[mt]);
            int col = (nt + 1) * 16 + cb;
#pragma unroll
            for (int mt = 0; mt < MT; ++mt)
#pragma unroll
                for (int i = 0; i < 4; ++i) {
                    int row = m0 + mt * 16 + rq + i;
                    if (row < M) C[(size_t)row * NMAT + col] = (__bf16)acc[mt][i];
                }
        }
    }
}

// ------------------------- MFMA GEMM + fused LayerNorm ----------------------
// Nmat = 128. EMB: A fp32, y = LN(relu(A@B + bias)); else A bf16,
// y = LN(resid + A@B). Writes fp32 hout and bf16 hbf. B prefetched.

template <int K, int MT, bool EMB>
__global__ __launch_bounds__(256) void gemm_ln(const void* __restrict__ Av,
                                               const __bf16* __restrict__ BT,
                                               const float* __restrict__ bias,
                                               const float* resid,
                                               const float* __restrict__ g,
                                               const float* __restrict__ beta,
                                               float* hout, __bf16* __restrict__ hbf,
                                               int M) {
    int wid = (blockIdx.x * 256 + threadIdx.x) >> 6;
    int lane = threadIdx.x & 63;
    int m0 = wid * 16 * MT;
    if (m0 >= M) return;
    constexpr int KS = K / 32;
    int cb = lane & 15;
    int kc = (lane >> 4) * 8;
    int rq = (lane >> 4) * 4;

    bf16x8 a[MT][KS];
#pragma unroll
    for (int mt = 0; mt < MT; ++mt) {
        int arow = m0 + mt * 16 + cb;
        if (arow >= M) arow = M - 1;
        if constexpr (EMB) {
            const float* A = (const float*)Av;
#pragma unroll
            for (int ks = 0; ks < KS; ++ks) {
                float4 u0 = *(const float4*)&A[(size_t)arow * K + ks * 32 + kc];
                float4 u1 = *(const float4*)&A[(size_t)arow * K + ks * 32 + kc + 4];
                bf16x8 av;
                av[0] = (__bf16)u0.x; av[1] = (__bf16)u0.y; av[2] = (__bf16)u0.z; av[3] = (__bf16)u0.w;
                av[4] = (__bf16)u1.x; av[5] = (__bf16)u1.y; av[6] = (__bf16)u1.z; av[7] = (__bf16)u1.w;
                a[mt][ks] = av;
            }
        } else {
            const __bf16* A = (const __bf16*)Av;
#pragma unroll
            for (int ks = 0; ks < KS; ++ks)
                a[mt][ks] = *(const bf16x8*)&A[(size_t)arow * K + ks * 32 + kc];
        }
    }

    const __bf16* bbase = &BT[(size_t)cb * K + kc];
    bf16x8 bA[KS], bB[KS];
#pragma unroll
    for (int ks = 0; ks < KS; ++ks) bA[ks] = *(const bf16x8*)(bbase + ks * 32);

    f32x4 acc[MT][8];
#pragma unroll
    for (int mt = 0; mt < MT; ++mt)
#pragma unroll
        for (int nt = 0; nt < 8; ++nt) acc[mt][nt] = (f32x4){0.f, 0.f, 0.f, 0.f};

#pragma unroll
    for (int nt = 0; nt < 8; nt += 2) {
#pragma unroll
        for (int ks = 0; ks < KS; ++ks)
            bB[ks] = *(const bf16x8*)(bbase + (size_t)(nt + 1) * 16 * K + ks * 32);
#pragma unroll
        for (int ks = 0; ks < KS; ++ks)
#pragma unroll
            for (int mt = 0; mt < MT; ++mt)
                acc[mt][nt] = MFMA16(a[mt][ks], bA[ks], acc[mt][nt]);
        if (nt + 2 < 8) {
#pragma unroll
            for (int ks = 0; ks < KS; ++ks)
                bA[ks] = *(const bf16x8*)(bbase + (size_t)(nt + 2) * 16 * K + ks * 32);
        }
#pragma unroll
        for (int ks = 0; ks < KS; ++ks)
#pragma unroll
            for (int mt = 0; mt < MT; ++mt)
                acc[mt][nt + 1] = MFMA16(a[mt][ks], bB[ks], acc[mt][nt + 1]);
    }

    // epilogue: bias/relu or residual
#pragma unroll
    for (int nt = 0; nt < 8; ++nt) {
        int col = nt * 16 + cb;
        float bb = EMB ? bias[col] : 0.f;
#pragma unroll
        for (int mt = 0; mt < MT; ++mt)
#pragma unroll
            for (int i = 0; i < 4; ++i) {
                float v = acc[mt][nt][i];
                if (EMB) {
                    v = fmaxf(v + bb, 0.f);
                } else {
                    int row = m0 + mt * 16 + rq + i;
                    if (row >= M) row = M - 1;
                    v += resid[(size_t)row * 128 + col];
                }
                acc[mt][nt][i] = v;
            }
    }

    float s[MT][4], qs[MT][4];
#pragma unroll
    for (int mt = 0; mt < MT; ++mt)
#pragma unroll
        for (int i = 0; i < 4; ++i) { s[mt][i] = 0.f; qs[mt][i] = 0.f; }
#pragma unroll
    for (int nt = 0; nt < 8; ++nt)
#pragma unroll
        for (int mt = 0; mt < MT; ++mt)
#pragma unroll
            for (int i = 0; i < 4; ++i) {
                float v = acc[mt][nt][i];
                s[mt][i] += v;
                qs[mt][i] += v * v;
            }
#pragma unroll
    for (int mt = 0; mt < MT; ++mt)
#pragma unroll
        for (int i = 0; i < 4; ++i)
#pragma unroll
            for (int o = 1; o < 16; o <<= 1) {
                s[mt][i] += __shfl_xor(s[mt][i], o);
                qs[mt][i] += __shfl_xor(qs[mt][i], o);
            }
    float mu[MT][4], rstd[MT][4];
#pragma unroll
    for (int mt = 0; mt < MT; ++mt)
#pragma unroll
        for (int i = 0; i < 4; ++i) {
            mu[mt][i] = s[mt][i] * (1.f / 128.f);
            float var = qs[mt][i] * (1.f / 128.f) - mu[mt][i] * mu[mt][i];
            rstd[mt][i] = rsqrtf(var + 1e-5f);
        }

#pragma unroll
    for (int nt = 0; nt < 8; ++nt) {
        int col = nt * 16 + cb;
        float gv = g[col], bv = beta[col];
#pragma unroll
        for (int mt = 0; mt < MT; ++mt)
#pragma unroll
            for (int i = 0; i < 4; ++i) {
                int row = m0 + mt * 16 + rq + i;
                if (row >= M) continue;
                float y = (acc[mt][nt][i] - mu[mt][i]) * rstd[mt][i] * gv + bv;
                size_t idx = (size_t)row * 128 + col;
                hout[idx] = y;
                hbf[idx] = (__bf16)y;
            }
    }
}

// ------------------------- attention (16 lanes x 4 edge slots) --------------

__global__ __launch_bounds__(256) void attn_gat(const __bf16* __restrict__ qkv,
                                                const int* __restrict__ row_ptr,
                                                const int* __restrict__ csr_src,
                                                __bf16* __restrict__ agg, int N) {
    int wave = threadIdx.x >> 6;
    int lane = threadIdx.x & 63;
    int n = blockIdx.x * 4 + wave;
    if (n >= N) return;
    int j = lane >> 4, q16 = lane & 15, c0 = q16 * 8;
    const float scale = 0.25f;  // 1/sqrt(16)

    bf16x8 qv = *(const bf16x8*)&qkv[(size_t)n * 384 + c0];
    float qf[8];
#pragma unroll
    for (int i = 0; i < 8; ++i) qf[i] = (float)qv[i];

    int e0 = row_ptr[n], e1 = row_ptr[n + 1];
    float m = -3e38f, s = 0.f;
    float acc[8] = {0.f, 0.f, 0.f, 0.f, 0.f, 0.f, 0.f, 0.f};

    for (int base = e0; base < e1; base += 4) {
        int e = base + j;
        bool valid = e < e1;
        int src = csr_src[valid ? e : e0];
        const __bf16* kp = &qkv[(size_t)src * 384 + 128 + c0];
        bf16x8 kv = *(const bf16x8*)kp;
        bf16x8 vv = *(const bf16x8*)(kp + 128);
        float d = 0.f;
#pragma unroll
        for (int i = 0; i < 8; ++i) d = fmaf(qf[i], (float)kv[i], d);
        d += __shfl_xor(d, 1);
        float sc = d * scale;
        if (valid) {
            float mn = fmaxf(m, sc);
            float f = __expf(m - mn), p = __expf(sc - mn);
            s = s * f + p;
#pragma unroll
            for (int i = 0; i < 8; ++i) acc[i] = acc[i] * f + p * (float)vv[i];
            m = mn;
        }
    }

#pragma unroll
    for (int off = 16; off <= 32; off <<= 1) {
        float mo_ = __shfl_xor(m, off);
        float so_ = __shfl_xor(s, off);
        float mn = fmaxf(m, mo_);
        float f = __expf(m - mn), fo = __expf(mo_ - mn);
        s = s * f + so_ * fo;
#pragma unroll
        for (int i = 0; i < 8; ++i)
            acc[i] = acc[i] * f + __shfl_xor(acc[i], off) * fo;
        m = mn;
    }

    if (j == 0) {
        float inv = (s > 0.f) ? 1.f / s : 0.f;
        bf16x8 o;
#pragma unroll
        for (int i = 0; i < 8; ++i) o[i] = (__bf16)(acc[i] * inv);
        *(bf16x8*)&agg[(size_t)n * 128 + c0] = o;
    }
}

// ------------------------- FFN head (MFMA, 3 phases) ------------------------
// Block = 256 threads (4 waves), 64 rows. Wave w owns cols [w*128, w*128+128).
// h[64][128] -> h1[64][512] (LDS, XOR-swizzled) -> h2 (same LDS) -> out[64][47].
// Phase 2: K fully unrolled, B parity-double-buffered one K-step ahead.

__global__ __launch_bounds__(256, 2) void ffn_mfma(const __bf16* __restrict__ hbf,
                                                   const __bf16* __restrict__ f1T,
                                                   const float* __restrict__ f1b,
                                                   const __bf16* __restrict__ f2T,
                                                   const float* __restrict__ f2b,
                                                   const __bf16* __restrict__ f3T,
                                                   const float* __restrict__ f3b,
                                                   float* __restrict__ out, int M) {
    __shared__ __bf16 hbuf[64 * 512];  // 64 KB; byte = rl*1024 + col*2, ^((rl&7)<<4)
    int w = threadIdx.x >> 6;
    int lane = threadIdx.x & 63;
    int r0 = blockIdx.x * 64;
    int cb = lane & 15;
    int kc = (lane >> 4) * 8;
    int rq = (lane >> 4) * 4;
    char* hb = (char*)hbuf;

    // ---- phase 1: h1 = relu(h @ f1w + b1); 4 m-tiles, 8 n-tiles per wave
    {
        bf16x8 a1[4][4];
#pragma unroll
        for (int mt = 0; mt < 4; ++mt) {
            int row = r0 + mt * 16 + cb;
            if (row >= M) row = M - 1;
#pragma unroll
            for (int ks = 0; ks < 4; ++ks)
                a1[mt][ks] = *(const bf16x8*)&hbf[(size_t)row * 128 + ks * 32 + kc];
        }
        const __bf16* b1base = &f1T[(size_t)(w * 128 + cb) * 128 + kc];
        bf16x8 bA[4], bB[4];
#pragma unroll
        for (int ks = 0; ks < 4; ++ks) bA[ks] = *(const bf16x8*)(b1base + ks * 32);
#pragma unroll
        for (int nt = 0; nt < 8; nt += 2) {
#pragma unroll
            for (int ks = 0; ks < 4; ++ks)
                bB[ks] = *(const bf16x8*)(b1base + (size_t)(nt + 1) * 16 * 128 + ks * 32);
            {
                f32x4 acc[4];
#pragma unroll
                for (int mt = 0; mt < 4; ++mt) acc[mt] = (f32x4){0.f, 0.f, 0.f, 0.f};
#pragma unroll
                for (int ks = 0; ks < 4; ++ks)
#pragma unroll
                    for (int mt = 0; mt < 4; ++mt)
                        acc[mt] = MFMA16(a1[mt][ks], bA[ks], acc[mt]);
                int ncol = w * 128 + nt * 16;
                float bb = f1b[ncol + cb];
#pragma unroll
                for (int mt = 0; mt < 4; ++mt)
#pragma unroll
                    for (int i = 0; i < 4; ++i) {
                        int rl = mt * 16 + rq + i;
                        int byte = (rl * 1024 + (ncol + cb) * 2) ^ ((rl & 7) << 4);
                        *(__bf16*)(hb + byte) = (__bf16)fmaxf(acc[mt][i] + bb, 0.f);
                    }
            }
            if (nt + 2 < 8) {
#pragma unroll
                for (int ks = 0; ks < 4; ++ks)
                    bA[ks] = *(const bf16x8*)(b1base + (size_t)(nt + 2) * 16 * 128 + ks * 32);
            }
            {
                f32x4 acc[4];
#pragma unroll
                for (int mt = 0; mt < 4; ++mt) acc[mt] = (f32x4){0.f, 0.f, 0.f, 0.f};
#pragma unroll
                for (int ks = 0; ks < 4; ++ks)
#pragma unroll
                    for (int mt = 0; mt < 4; ++mt)
                        acc[mt] = MFMA16(a1[mt][ks], bB[ks], acc[mt]);
                int ncol = w * 128 + (nt + 1) * 16;
                float bb = f1b[ncol + cb];
#pragma unroll
                for (int mt = 0; mt < 4; ++mt)
#pragma unroll
                    for (int i = 0; i < 4; ++i) {
                        int rl = mt * 16 + rq + i;
                        int byte = (rl * 1024 + (ncol + cb) * 2) ^ ((rl & 7) << 4);
                        *(__bf16*)(hb + byte) = (__bf16)fmaxf(acc[mt][i] + bb, 0.f);
                    }
            }
        }
    }
    __syncthreads();

    // ---- phase 2: h2 = relu(h1 @ f2w + b2); K=512 (16 steps), B 1-step ahead
    {
        f32x4 acc2[4][8];
#pragma unroll
        for (int mt = 0; mt < 4; ++mt)
#pragma unroll
            for (int nt = 0; nt < 8; ++nt) acc2[mt][nt] = (f32x4){0.f, 0.f, 0.f, 0.f};

        const __bf16* bpn[8];
#pragma unroll
        for (int nt = 0; nt < 8; ++nt)
            bpn[nt] = &f2T[(size_t)(w * 128 + nt * 16 + cb) * 512 + kc];

        bf16x8 b0[8], b1[8];
#pragma unroll
        for (int nt = 0; nt < 8; ++nt) b0[nt] = *(const bf16x8*)bpn[nt];

#pragma unroll
        for (int ks = 0; ks < 16; ks += 2) {
            // prefetch ks+1
#pragma unroll
            for (int nt = 0; nt < 8; ++nt)
                b1[nt] = *(const bf16x8*)(bpn[nt] + (ks + 1) * 32);
            {
                bf16x8 a2[4];
#pragma unroll
                for (int mt = 0; mt < 4; ++mt) {
                    int rl = mt * 16 + cb;
                    int byte = (rl * 1024 + (ks * 32 + kc) * 2) ^ ((rl & 7) << 4);
                    a2[mt] = *(const bf16x8*)(hb + byte);
                }
#pragma unroll
                for (int nt = 0; nt < 8; ++nt)
#pragma unroll
                    for (int mt = 0; mt < 4; ++mt)
                        acc2[mt][nt] = MFMA16(a2[mt], b0[nt], acc2[mt][nt]);
            }
            // prefetch ks+2
            if (ks + 2 < 16) {
#pragma unroll
                for (int nt = 0; nt < 8; ++nt)
                    b0[nt] = *(const bf16x8*)(bpn[nt] + (ks + 2) * 32);
            }
            {
                bf16x8 a2[4];
#pragma unroll
                for (int mt = 0; mt < 4; ++mt) {
                    int rl = mt * 16 + cb;
                    int byte = (rl * 1024 + ((ks + 1) * 32 + kc) * 2) ^ ((rl & 7) << 4);
                    a2[mt] = *(const bf16x8*)(hb + byte);
                }
#pragma unroll
                for (int nt = 0; nt < 8; ++nt)
#pragma unroll
                    for (int mt = 0; mt < 4; ++mt)
                        acc2[mt][nt] = MFMA16(a2[mt], b1[nt], acc2[mt][nt]);
            }
        }
        __syncthreads();  // all h1 reads done before overwrite
#pragma unroll
        for (int nt = 0; nt < 8; ++nt) {
            int ncol = w * 128 + nt * 16;
            float bb = f2b[ncol + cb];
#pragma unroll
            for (int mt = 0; mt < 4; ++mt)
#pragma unroll
                for (int i = 0; i < 4; ++i) {
                    int rl = mt * 16 + rq + i;
                    int byte = (rl * 1024 + (ncol + cb) * 2) ^ ((rl & 7) << 4);
                    *(__bf16*)(hb + byte) = (__bf16)fmaxf(acc2[mt][nt][i] + bb, 0.f);
                }
        }
    }
    __syncthreads();

    // ---- phase 3: out = h2 @ f3w + b3; wave w -> m-tile w, n-tiles 0..2
    {
        f32x4 acc3[3];
#pragma unroll
        for (int nt = 0; nt < 3; ++nt) acc3[nt] = (f32x4){0.f, 0.f, 0.f, 0.f};
#pragma unroll
        for (int ks = 0; ks < 16; ++ks) {
            int rl = w * 16 + cb;
            int byte = (rl * 1024 + (ks * 32 + kc) * 2) ^ ((rl & 7) << 4);
            bf16x8 a3 = *(const bf16x8*)(hb + byte);
#pragma unroll
            for (int nt = 0; nt < 3; ++nt) {
                bf16x8 b = *(const bf16x8*)&f3T[(size_t)(nt * 16 + cb) * 512 + ks * 32 + kc];
                acc3[nt] = MFMA16(a3, b, acc3[nt]);
            }
        }
#pragma unroll
        for (int nt = 0; nt < 3; ++nt) {
            int col = nt * 16 + cb;
            if (col < 47) {
                float bb = f3b[col];
                int r = r0 + w * 16 + rq;
#pragma unroll
                for (int i = 0; i < 4; ++i)
                    if (r + i < M) out[(size_t)(r + i) * 47 + col] = acc3[nt][i] + bb;
            }
        }
    }
}

// ------------------------- launch -------------------------------------------

extern "C" void kernel_launch(void* const* d_in, const int* in_sizes, int n_in,
                              void* d_out, int out_size, void* d_ws, size_t ws_size,
                              hipStream_t stream) {
    const float* X        = (const float*)d_in[0];
    const int*   ei       = (const int*)d_in[1];
    const float* emb_w    = (const float*)d_in[2];
    const float* emb_b    = (const float*)d_in[3];
    const float* emb_ln_g = (const float*)d_in[4];
    const float* emb_ln_b = (const float*)d_in[5];
    const float* Wq       = (const float*)d_in[6];
    const float* Wk       = (const float*)d_in[7];
    const float* Wv       = (const float*)d_in[8];
    const float* Wo       = (const float*)d_in[9];
    const float* ln_g     = (const float*)d_in[10];
    const float* ln_b     = (const float*)d_in[11];
    const float* f1w      = (const float*)d_in[12];
    const float* f1b      = (const float*)d_in[13];
    const float* f2w      = (const float*)d_in[14];
    const float* f2b      = (const float*)d_in[15];
    const float* f3w      = (const float*)d_in[16];
    const float* f3b      = (const float*)d_in[17];

    const int N = in_sizes[0] / 256;  // 50000
    const int E = in_sizes[1] / 2;    // 640000
    const int NB = (N + 1023) / 1024;

    // ---- workspace layout
    char* p = (char*)d_ws;
    float* h = (float*)p;            p += (size_t)N * 128 * 4;
    __bf16* hbf = (__bf16*)p;        p += (size_t)N * 128 * 2;
    __bf16* qkv = (__bf16*)p;        p += (size_t)N * 384 * 2;
    __bf16* aggb = (__bf16*)p;       p += (size_t)N * 128 * 2;
    __bf16* embT = (__bf16*)p;       p += 128 * 256 * 2;
    __bf16* qkvT = (__bf16*)p;       p += 3 * 384 * 128 * 2;
    __bf16* woT = (__bf16*)p;        p += 3 * 128 * 128 * 2;
    __bf16* f1T = (__bf16*)p;        p += 512 * 128 * 2;
    __bf16* f2T = (__bf16*)p;        p += 512 * 512 * 2;
    __bf16* f3T = (__bf16*)p;        p += 48 * 512 * 2;
    int* deg = (int*)p;              p += (size_t)N * 4;
    int* cursor = (int*)p;           p += (size_t)N * 4;
    int* row_ptr = (int*)p;          p += (size_t)(N + 1) * 4;
    int* csr_src = (int*)p;          p += (size_t)E * 4;
    int* partials = (int*)p;

    // ---- CSR build
    zero_ints<<<(2 * N + 255) / 256, 256, 0, stream>>>(deg, 2 * N);
    count_deg<<<(E + 255) / 256, 256, 0, stream>>>(ei, deg, E);
    scan_part<<<NB, 256, 0, stream>>>(deg, partials, N);
    scan_mid<<<1, 64, 0, stream>>>(partials, row_ptr, NB, N);
    scan_final<<<NB, 256, 0, stream>>>(deg, partials, row_ptr, N);
    scatter_edges<<<(E + 255) / 256, 256, 0, stream>>>(ei, row_ptr, cursor, csr_src, E);

    transpose_all<<<576, 256, 0, stream>>>(emb_w, f1w, f2w, f3w, Wq, Wk, Wv, Wo,
                                           embT, f1T, f2T, f3T, qkvT, woT);

    int gw16 = ((N + 15) / 16 + 3) / 4;   // MT=1 waves
    int gw32 = ((N + 31) / 32 + 3) / 4;   // MT=2 waves
    int gw64 = ((N + 63) / 64 + 3) / 4;   // MT=4 waves

    // ---- embedding: LN(relu(X @ emb_w + emb_b)) -> h (fp32) + hbf
    gemm_ln<256, 1, true><<<gw16, 256, 0, stream>>>(X, embT, emb_b, nullptr,
                                                    emb_ln_g, emb_ln_b, h, hbf, N);

    // ---- layers
    for (int l = 0; l < 3; ++l) {
        gemm_bf16<128, 24, 4><<<gw64, 256, 0, stream>>>(hbf, qkvT + (size_t)l * 49152,
                                                        qkv, N);
        attn_gat<<<(N + 3) / 4, 256, 0, stream>>>(qkv, row_ptr, csr_src, aggb, N);
        gemm_ln<128, 2, false><<<gw32, 256, 0, stream>>>(aggb, woT + (size_t)l * 16384,
                                                         nullptr, h,
                                                         ln_g + (size_t)l * 128,
                                                         ln_b + (size_t)l * 128, h, hbf, N);
    }

    // ---- FFN head
    ffn_mfma<<<(N + 63) / 64, 256, 0, stream>>>(hbf, f1T, f1b, f2T, f2b, f3T, f3b,
                                                (float*)d_out, N);
}